// Round 7
// baseline (3138.018 us; speedup 1.0000x reference)
//
#include <hip/hip_runtime.h>
#include <hip/hip_bf16.h>
#include <math.h>

typedef __attribute__((ext_vector_type(8))) short short8;
typedef __attribute__((ext_vector_type(4))) float f32x4;
typedef __hip_bfloat16 bf16;

#define BB 2
#define TT 16
#define SSQ 257
#define DIMD 512
#define NROWS 8224          // B*T*S ( = 514 * 16 exactly)
#define DII 1365
#define DI2 2730
#define GLUK 1408           // glu K (44*32); kq8 = 176
#define SKP 288             // padded key count for space attn
#define EPSR 1.1920929e-07f

// Fragment-major packed layout: X_pk[t16][kq][l16][8] (shorts): frag load at
// (t16, kt) is lane-linear: base + ((t16*kq8 + kt*4)*128 + lane*8).

__device__ __forceinline__ short f2bfs(float x) {
    bf16 h = __float2bfloat16(x);
    return *reinterpret_cast<short*>(&h);
}

__device__ __forceinline__ size_t pk_idx(int row, int col, int kq8) {
    return ((size_t)((row >> 4) * kq8 + (col >> 3)) * 16 + (row & 15)) * 8 + (col & 7);
}

// ---------------- batched per-layer weight transpose fp32->bf16, packed ----------------
__global__ void wtrans_layer(const float* __restrict__ wq, const float* __restrict__ wk,
                             const float* __restrict__ wv, const float* __restrict__ wo,
                             const float* __restrict__ win, const float* __restrict__ wout,
                             bf16* __restrict__ dqkv, bf16* __restrict__ dwo,
                             bf16* __restrict__ dwin, bf16* __restrict__ dwout) {
    __shared__ float tile[32][33];
    int bid = blockIdx.x;
    const float* src; bf16* dst; int K, M, Kpad, interleave = 0, local, nbase = 0;
    if (bid < 512)       { src = wq;   dst = dqkv; K = 512;  M = 1024; Kpad = 512;  local = bid; }
    else if (bid < 768)  { src = wk;   dst = dqkv; K = 512;  M = 512;  Kpad = 512;  local = bid - 512;  nbase = 1024; }
    else if (bid < 1024) { src = wv;   dst = dqkv; K = 512;  M = 512;  Kpad = 512;  local = bid - 768;  nbase = 1536; }
    else if (bid < 1536) { src = wo;   dst = dwo;  K = 1024; M = 512;  Kpad = 1024; local = bid - 1024; }
    else if (bid < 2944) { src = win;  dst = dwin; K = 512;  M = 2730; Kpad = 512;  local = bid - 1536; interleave = 1; }
    else                 { src = wout; dst = dwout;K = 1365; M = 512;  Kpad = 1408; local = bid - 2944; }
    int tilesx = Kpad >> 5;
    int k0 = (local % tilesx) * 32, m0 = (local / tilesx) * 32;
    int tx = threadIdx.x & 31, ty = threadIdx.x >> 5;
    #pragma unroll
    for (int i = 0; i < 4; ++i) {
        int k = k0 + ty + 8 * i, m = m0 + tx;
        tile[ty + 8 * i][tx] = (k < K && m < M) ? src[(size_t)k * M + m] : 0.f;
    }
    __syncthreads();
    #pragma unroll
    for (int i = 0; i < 4; ++i) {
        int n = m0 + ty + 8 * i, k = k0 + tx;
        int nd = n;
        if (interleave) nd = (n < DII) ? 2 * n : ((n < DI2) ? 2 * (n - DII) + 1 : n);
        nd += nbase;
        dst[pk_idx(nd, k, Kpad >> 3)] = __float2bfloat16(tile[tx][ty + 8 * i]);
    }
}

// ---------------- RMSNorm (optional permuted read); bf16 out packed kq8=64 ----------------
template<int BF16OUT>
__global__ void rms_kernel(const float* __restrict__ x, const float* __restrict__ w,
                           void* __restrict__ out, int perm) {
    int r = blockIdx.x;
    int src = r;
    if (perm) {
        int t = r & 15; int rs = r >> 4; int s = rs % SSQ; int b = rs / SSQ;
        src = (b * TT + t) * SSQ + s;
    }
    const float* xr = x + (size_t)src * DIMD;
    int tid = threadIdx.x;
    float v0 = xr[tid], v1 = xr[tid + 256];
    __shared__ float red[256];
    red[tid] = v0 * v0 + v1 * v1;
    __syncthreads();
    for (int st = 128; st; st >>= 1) {
        if (tid < st) red[tid] += red[tid + st];
        __syncthreads();
    }
    float sc = rsqrtf(red[0] * (1.f / DIMD) + EPSR);
    if (BF16OUT) {
        bf16* o = (bf16*)out;
        o[pk_idx(r, tid, 64)]       = __float2bfloat16(v0 * sc * w[tid]);
        o[pk_idx(r, tid + 256, 64)] = __float2bfloat16(v1 * sc * w[tid + 256]);
    } else {
        float* o = (float*)out + (size_t)r * DIMD;
        o[tid] = v0 * sc * w[tid];
        o[tid + 256] = v1 * sc * w[tid + 256];
    }
}

// ---------------- MFMA bf16 GEMM, no LDS / no barriers, K templated ----------------
// Fully-unrolled K-loop, 3-stage register pipeline (prefetch distance 2),
// XCD-aware tile swizzle. EPI: 1 = qkv + fused l2norm/gamma/rotary;
// 2 = glu packed out (tanh-gelu); 3 = fp32 accumulate (+bias, opt PERM).
template<int EPI, int PERM, int TM, int K>
__global__ __launch_bounds__(256)
void mfma_gemm(const short* __restrict__ Apk, const short* __restrict__ Bpk,
               const float* __restrict__ bias, void* __restrict__ C, int ldc,
               int nrow,
               const float* __restrict__ qg, const float* __restrict__ kg, int rotary) {
    constexpr int MI = TM / 32;
    constexpr int nk = K / 32;
    constexpr int kq8 = K / 8;
    int tid = threadIdx.x;
    int wave = tid >> 6, lane = tid & 63;
    int quad = lane >> 4, l16 = lane & 15;

    // XCD swizzle: blocks with lin%8==x cover a contiguous n-major tile range.
    int lin = blockIdx.y * gridDim.x + blockIdx.x;
    int total = gridDim.x * gridDim.y;
    int xc = lin & 7, jj = lin >> 3;
    int per = total >> 3, rem = total & 7;
    int base = xc * per + (xc < rem ? xc : rem);
    int t = base + jj;
    int gy = gridDim.y;
    int m0 = (t % gy) * TM, n0 = (t / gy) * 128;

    int wm = (wave & 1) * (TM / 2), wn = (wave >> 1) * 64;
    int mt0 = (m0 + wm) >> 4, nt0 = (n0 + wn) >> 4;

    const short* ab[MI]; const short* bb[4];
    #pragma unroll
    for (int mi = 0; mi < MI; ++mi) ab[mi] = Apk + (size_t)(mt0 + mi) * kq8 * 128 + lane * 8;
    #pragma unroll
    for (int nj = 0; nj < 4; ++nj)  bb[nj] = Bpk + (size_t)(nt0 + nj) * kq8 * 128 + lane * 8;

    f32x4 zero4 = {0.f, 0.f, 0.f, 0.f};
    f32x4 acc[MI][4];
    #pragma unroll
    for (int i = 0; i < MI; ++i)
        #pragma unroll
        for (int j = 0; j < 4; ++j) acc[i][j] = zero4;

    short8 Af[3][MI], Bf[3][4];
    #pragma unroll
    for (int mi = 0; mi < MI; ++mi) Af[0][mi] = *(const short8*)(ab[mi]);
    #pragma unroll
    for (int nj = 0; nj < 4; ++nj)  Bf[0][nj] = *(const short8*)(bb[nj]);
    #pragma unroll
    for (int mi = 0; mi < MI; ++mi) Af[1][mi] = *(const short8*)(ab[mi] + 512);
    #pragma unroll
    for (int nj = 0; nj < 4; ++nj)  Bf[1][nj] = *(const short8*)(bb[nj] + 512);

    #pragma unroll
    for (int kt = 0; kt < nk; ++kt) {
        if (kt + 2 < nk) {
            const int s = (kt + 2) % 3;
            #pragma unroll
            for (int mi = 0; mi < MI; ++mi) Af[s][mi] = *(const short8*)(ab[mi] + (size_t)(kt + 2) * 512);
            #pragma unroll
            for (int nj = 0; nj < 4; ++nj)  Bf[s][nj] = *(const short8*)(bb[nj] + (size_t)(kt + 2) * 512);
        }
        const int c = kt % 3;
        #pragma unroll
        for (int mi = 0; mi < MI; ++mi)
            #pragma unroll
            for (int nj = 0; nj < 4; ++nj)
                acc[mi][nj] = __builtin_amdgcn_mfma_f32_16x16x32_bf16(
                    Af[c][mi], Bf[c][nj], acc[mi][nj], 0, 0, 0);
    }

    if constexpr (EPI == 1) {
        // qkv output: cols wn..wn+63 = exactly one head.
        int head = (n0 + wn) >> 6;          // 0..15 q, 16..23 k, 24..31 v
        float gl0 = 0.f, gl1 = 0.f, gl2 = 0.f, gl3 = 0.f, inv0 = 0.f, inv1 = 0.f;
        if (head < 24) {
            const float* g = head < 16 ? qg + head * 64 : kg + (head - 16) * 64;
            gl0 = (g[l16] + 1.f) * 8.f;
            gl1 = (g[16 + l16] + 1.f) * 8.f;
            gl2 = (g[32 + l16] + 1.f) * 8.f;
            gl3 = (g[48 + l16] + 1.f) * 8.f;
            if (rotary) {
                inv0 = __expf(-(float)l16 * 0.28782313662425572f);        // ln(1e4)/32
                inv1 = __expf(-(float)(l16 + 16) * 0.28782313662425572f);
            }
        }
        #pragma unroll
        for (int mi = 0; mi < MI; ++mi) {
            #pragma unroll
            for (int e = 0; e < 4; ++e) {
                int row = m0 + wm + mi * 16 + quad * 4 + e;
                float v0 = acc[mi][0][e], v1 = acc[mi][1][e];
                float v2 = acc[mi][2][e], v3 = acc[mi][3][e];
                if (head < 24) {
                    float ss = v0 * v0 + v1 * v1 + v2 * v2 + v3 * v3;
                    ss += __shfl_xor(ss, 1); ss += __shfl_xor(ss, 2);
                    ss += __shfl_xor(ss, 4); ss += __shfl_xor(ss, 8);
                    float invn = 1.f / fmaxf(sqrtf(ss), 1e-12f);
                    v0 *= invn * gl0; v1 *= invn * gl1;
                    v2 *= invn * gl2; v3 *= invn * gl3;
                    if (rotary) {
                        float tt = (float)(row & 15);
                        float a0v = tt * inv0, a1v = tt * inv1;
                        float c0 = __cosf(a0v), s0 = __sinf(a0v);
                        float c1 = __cosf(a1v), s1 = __sinf(a1v);
                        float n0v = v0 * c0 - v2 * s0;
                        float n1v = v1 * c1 - v3 * s1;
                        float n2v = v2 * c0 + v0 * s0;
                        float n3v = v3 * c1 + v1 * s1;
                        v0 = n0v; v1 = n1v; v2 = n2v; v3 = n3v;
                    }
                }
                if (row < nrow) {
                    bf16* p = (bf16*)C + (size_t)row * ldc + n0 + wn + l16;
                    p[0]  = __float2bfloat16(v0);
                    p[16] = __float2bfloat16(v1);
                    p[32] = __float2bfloat16(v2);
                    p[48] = __float2bfloat16(v3);
                }
            }
        }
    } else if constexpr (EPI == 2) {
        // interleaved a/g; tanh-form gelu; write packed glu (kq8=176) at j=col/2.
        #pragma unroll
        for (int mi = 0; mi < MI; ++mi) {
            #pragma unroll
            for (int e = 0; e < 4; ++e) {
                int row = m0 + wm + mi * 16 + quad * 4 + e;
                #pragma unroll
                for (int nj = 0; nj < 4; ++nj) {
                    int col = n0 + wn + nj * 16 + l16;
                    int j = col >> 1;
                    float b = (j < DII) ? ((col & 1) ? bias[DII + j] : bias[j]) : 0.f;
                    float v = acc[mi][nj][e] + b;
                    float prt = __shfl_xor(v, 1);
                    if (!(l16 & 1) && row < nrow) {
                        float gv = prt;
                        float u = 0.7978845608028654f * (gv + 0.044715f * gv * gv * gv);
                        float e2u = __expf(2.f * u);
                        float th = 1.f - 2.f * __builtin_amdgcn_rcpf(e2u + 1.f);
                        float glu = v * 0.5f * gv * (1.f + th);
                        ((bf16*)C)[pk_idx(row, j, 176)] = __float2bfloat16(glu);
                    }
                }
            }
        }
    } else {
        #pragma unroll
        for (int mi = 0; mi < MI; ++mi) {
            #pragma unroll
            for (int e = 0; e < 4; ++e) {
                int row = m0 + wm + mi * 16 + quad * 4 + e;
                if (row >= nrow) continue;
                int orow = row;
                if (PERM) {
                    int tt = row & 15; int rs = row >> 4; int s = rs % SSQ; int b = rs / SSQ;
                    orow = (b * TT + tt) * SSQ + s;
                }
                #pragma unroll
                for (int nj = 0; nj < 4; ++nj) {
                    int col = n0 + wn + nj * 16 + l16;
                    float v = acc[mi][nj][e];
                    if (bias) v += bias[col];
                    ((float*)C)[(size_t)orow * ldc + col] += v;
                }
            }
        }
    }
}

// ---------------- V transpose for PV MFMA: vt[bt*8+kh][64][SKP] bf16 ----------------
__global__ void vtrans_kernel(const bf16* __restrict__ qkv, bf16* __restrict__ vt) {
    int bkh = blockIdx.x;          // bt*8 + kh
    int kc = blockIdx.y;           // key chunk of 32
    int bt = bkh >> 3, kh = bkh & 7;
    int tid = threadIdx.x;
    #pragma unroll
    for (int i = 0; i < 8; ++i) {
        int idx = tid + 256 * i;   // 0..2047
        int kl = idx >> 6;         // key local
        int d = idx & 63;
        int key = kc * 32 + kl;
        float v = 0.f;
        if (key < SSQ)
            v = __bfloat162float(qkv[((size_t)(bt * SSQ + key)) * 2048 + 1536 + kh * 64 + d]);
        vt[((size_t)bkh * 64 + d) * SKP + key] = __float2bfloat16(v);
    }
}

// ---------------- space attention: S^T in registers, zero LDS; ob packed out ----------------
__global__ __launch_bounds__(256)
void space_attn_kernel(const bf16* __restrict__ qkv, const bf16* __restrict__ vt,
                       bf16* __restrict__ obpk) {
    int qt = blockIdx.x, qh = blockIdx.y, bt = blockIdx.z;
    int kh = qh >> 1;
    int tid = threadIdx.x, wave = tid >> 6, lane = tid & 63;
    int quad = lane >> 4, l16 = lane & 15;
    int q0w = qt * 64 + wave * 16;
    int q = q0w + l16;
    int qc = q > 256 ? 256 : q;
    const short* qbase = (const short*)qkv + (size_t)bt * SSQ * 2048;
    const short* qp = qbase + (size_t)qc * 2048 + qh * 64;
    short8 bq0 = *(const short8*)(qp + quad * 8);
    short8 bq1 = *(const short8*)(qp + 32 + quad * 8);
    f32x4 zero4 = {0.f, 0.f, 0.f, 0.f};
    f32x4 sc[18];

    #pragma unroll
    for (int kt = 0; kt < 17; ++kt) {
        int keyl = kt * 16 + l16; if (keyl > 256) keyl = 256;
        const short* kp = qbase + (size_t)keyl * 2048 + 1024 + kh * 64;
        short8 ak0 = *(const short8*)(kp + quad * 8);
        short8 ak1 = *(const short8*)(kp + 32 + quad * 8);
        f32x4 c = zero4;
        c = __builtin_amdgcn_mfma_f32_16x16x32_bf16(ak0, bq0, c, 0, 0, 0);
        c = __builtin_amdgcn_mfma_f32_16x16x32_bf16(ak1, bq1, c, 0, 0, 0);
        #pragma unroll
        for (int e = 0; e < 4; ++e) {
            float e2x = __expf(c[e] * 0.005f);
            float v = 50.f - 100.f * __builtin_amdgcn_rcpf(e2x + 1.f);
            if (kt == 16) {
                bool valid = (e == 0) && (quad == 0) && (q == 256);
                v = valid ? v : -1e30f;
            }
            c[e] = v;
        }
        sc[kt] = c;
    }

    float mx = -1e30f;
    #pragma unroll
    for (int kt = 0; kt < 17; ++kt)
        mx = fmaxf(mx, fmaxf(fmaxf(sc[kt][0], sc[kt][1]), fmaxf(sc[kt][2], sc[kt][3])));
    mx = fmaxf(mx, __shfl_xor(mx, 16));
    mx = fmaxf(mx, __shfl_xor(mx, 32));
    float sum = 0.f;
    #pragma unroll
    for (int kt = 0; kt < 17; ++kt) {
        #pragma unroll
        for (int e = 0; e < 4; ++e) {
            float p = __expf(sc[kt][e] - mx);
            sc[kt][e] = p;
            sum += p;
        }
    }
    #pragma unroll
    for (int e = 0; e < 4; ++e) sc[17][e] = 0.f;
    sum += __shfl_xor(sum, 16);
    sum += __shfl_xor(sum, 32);
    float inv = __builtin_amdgcn_rcpf(sum);
    f32x4 inv4;
    #pragma unroll
    for (int e = 0; e < 4; ++e) inv4[e] = __shfl(inv, quad * 4 + e);

    f32x4 oacc[4];
    #pragma unroll
    for (int nt = 0; nt < 4; ++nt) oacc[nt] = zero4;
    const short* vbp = (const short*)vt + ((size_t)(bt * 8 + kh) * 64 + l16) * SKP;
    #pragma unroll
    for (int c8 = 0; c8 < 9; ++c8) {
        short8 pb;
        #pragma unroll
        for (int j = 0; j < 8; ++j) {
            int src_lane = ((quad & 1) * 2 + (j >> 2)) * 16 + l16;
            float v0 = __shfl(sc[2 * c8][j & 3], src_lane);
            float v1 = __shfl(sc[2 * c8 + 1][j & 3], src_lane);
            pb[j] = f2bfs(quad < 2 ? v0 : v1);
        }
        #pragma unroll
        for (int nt = 0; nt < 4; ++nt) {
            short8 av = *(const short8*)(vbp + (size_t)(nt * 16) * SKP + c8 * 32 + quad * 8);
            oacc[nt] = __builtin_amdgcn_mfma_f32_16x16x32_bf16(pb, av, oacc[nt], 0, 0, 0);
        }
    }

    #pragma unroll
    for (int e = 0; e < 4; ++e) {
        int qq = q0w + quad * 4 + e;
        if (qq <= 256) {
            int row = bt * SSQ + qq;
            float s = inv4[e];
            #pragma unroll
            for (int nt = 0; nt < 4; ++nt)
                obpk[pk_idx(row, qh * 64 + nt * 16 + l16, 128)] =
                    __float2bfloat16(oacc[nt][e] * s);
        }
    }
}

// ---------------- time attention (n=16, causal): one block per (b*s, qh) ----------------
__global__ void time_attn_kernel(const bf16* __restrict__ qkv, bf16* __restrict__ obpk) {
    __shared__ float qs[16][65], ks[16][65], ps[16][17];
    int bs = blockIdx.x, qh = blockIdx.y, kh = qh >> 1;
    int tid = threadIdx.x;
    size_t rowbase = (size_t)bs * 16;
    #pragma unroll
    for (int i = 0; i < 4; ++i) {
        int idx = tid + 256 * i;
        int r = idx >> 6, d = idx & 63;
        qs[r][d] = __bfloat162float(qkv[(rowbase + r) * 2048 + qh * 64 + d]);
        ks[r][d] = __bfloat162float(qkv[(rowbase + r) * 2048 + 1024 + kh * 64 + d]);
    }
    __syncthreads();
    int i = tid >> 4, j = tid & 15;
    float dot = 0.f;
    #pragma unroll 16
    for (int d = 0; d < 64; ++d) dot += qs[i][d] * ks[j][d];
    float s = dot * 0.125f;
    float ex = __expf(s * 0.04f);
    s = 50.f * (ex - 1.f) / (ex + 1.f);
    if (j > i) s = -1e30f;
    float mx = s;
    mx = fmaxf(mx, __shfl_xor(mx, 1));
    mx = fmaxf(mx, __shfl_xor(mx, 2));
    mx = fmaxf(mx, __shfl_xor(mx, 4));
    mx = fmaxf(mx, __shfl_xor(mx, 8));
    float p = __expf(s - mx);
    float sum = p;
    sum += __shfl_xor(sum, 1);
    sum += __shfl_xor(sum, 2);
    sum += __shfl_xor(sum, 4);
    sum += __shfl_xor(sum, 8);
    ps[i][j] = p / sum;
    __syncthreads();
    #pragma unroll
    for (int ii = 0; ii < 4; ++ii) {
        int idx = tid + 256 * ii;
        int r = idx >> 6, d = idx & 63;
        float acc = 0.f;
        #pragma unroll
        for (int jj = 0; jj < 16; ++jj)
            acc += ps[r][jj] * __bfloat162float(qkv[(rowbase + jj) * 2048 + 1536 + kh * 64 + d]);
        obpk[pk_idx((int)(rowbase + r), qh * 64 + d, 128)] = __float2bfloat16(acc);
    }
}

// ---------------- host-side launch ----------------
extern "C" void kernel_launch(void* const* d_in, const int* in_sizes, int n_in,
                              void* d_out, int out_size, void* d_ws, size_t ws_size,
                              hipStream_t stream) {
    const float* tokens      = (const float*)d_in[0];
    const float* attn_norm_w = (const float*)d_in[1];
    const float* Wq          = (const float*)d_in[2];
    const float* Wk          = (const float*)d_in[3];
    const float* Wv          = (const float*)d_in[4];
    const float* q_gamma     = (const float*)d_in[5];
    const float* k_gamma     = (const float*)d_in[6];
    const float* Wo          = (const float*)d_in[7];
    const float* ff_norm_w   = (const float*)d_in[8];
    const float* W_in        = (const float*)d_in[9];
    const float* b_in        = (const float*)d_in[10];
    const float* W_out       = (const float*)d_in[11];
    const float* b_out       = (const float*)d_in[12];
    const float* final_w     = (const float*)d_in[13];

    float* x = (float*)d_out;
    char* ws = (char*)d_ws;

    // packed per-layer weights (reused each layer)
    bf16* wtqkv = (bf16*)ws;                                  // N=2048, kq8=64:  2 MB
    bf16* wto   = (bf16*)(ws + 2097152);                      // N=512,  kq8=128: 1 MB
    bf16* wtin  = (bf16*)(ws + 2097152 + 1048576);            // N=2816, kq8=64:  2.9 MB
    bf16* wtout = (bf16*)(ws + 2097152 + 1048576 + 2883584);  // N=512,  kq8=176: 1.4 MB
    size_t off = 2097152 + 1048576 + 2883584 + 1441792;
    bf16* h_pk  = (bf16*)(ws + off);   off += (size_t)520 * 64 * 128 * 2;    // 8.5 MB
    bf16* ob_pk = (bf16*)(ws + off);   off += (size_t)520 * 128 * 128 * 2;   // 17 MB
    bf16* qkv   = (bf16*)(ws + off);                                          // 33.7 MB
    bf16* glu_pk= (bf16*)(ws + off);   off += (size_t)NROWS * 2048 * 2;      // (alias)
    bf16* vt    = (bf16*)(ws + off);                                          // 9.4 MB

    hipMemcpyAsync(x, tokens, (size_t)NROWS * 512 * 4, hipMemcpyDeviceToDevice, stream);

    for (int l = 0; l < 8; ++l) {
        int is_time = ((l + 1) % 4 == 0) ? 1 : 0;
        wtrans_layer<<<3648, 256, 0, stream>>>(
            Wq + (size_t)l * 512 * 1024, Wk + (size_t)l * 512 * 512,
            Wv + (size_t)l * 512 * 512, Wo + (size_t)l * 1024 * 512,
            W_in + (size_t)l * 512 * DI2, W_out + (size_t)l * DII * 512,
            wtqkv, wto, wtin, wtout);

        // ---- attention block ----
        rms_kernel<1><<<NROWS, 256, 0, stream>>>(x, attn_norm_w + (size_t)l * 512, h_pk, is_time);
        mfma_gemm<1, 0, 128, 512><<<dim3(16, 65), 256, 0, stream>>>(
            (const short*)h_pk, (const short*)wtqkv, nullptr, qkv, 2048, NROWS,
            q_gamma + (size_t)l * 1024, k_gamma + (size_t)l * 512, is_time);
        if (is_time) {
            time_attn_kernel<<<dim3(514, 16), 256, 0, stream>>>(qkv, ob_pk);
            mfma_gemm<3, 1, 64, 1024><<<dim3(4, 129), 256, 0, stream>>>(
                (const short*)ob_pk, (const short*)wto, nullptr, x, 512, NROWS,
                nullptr, nullptr, 0);
        } else {
            vtrans_kernel<<<dim3(256, 9), 256, 0, stream>>>(qkv, vt);
            space_attn_kernel<<<dim3(5, 16, 32), 256, 0, stream>>>(qkv, vt, ob_pk);
            mfma_gemm<3, 0, 64, 1024><<<dim3(4, 129), 256, 0, stream>>>(
                (const short*)ob_pk, (const short*)wto, nullptr, x, 512, NROWS,
                nullptr, nullptr, 0);
        }

        // ---- feed-forward block ----
        rms_kernel<1><<<NROWS, 256, 0, stream>>>(x, ff_norm_w + (size_t)l * 512, h_pk, 0);
        mfma_gemm<2, 0, 128, 512><<<dim3(22, 65), 256, 0, stream>>>(
            (const short*)h_pk, (const short*)wtin, b_in + (size_t)l * DI2, glu_pk, 0,
            NROWS, nullptr, nullptr, 0);
        mfma_gemm<3, 0, 64, GLUK><<<dim3(4, 129), 256, 0, stream>>>(
            (const short*)glu_pk, (const short*)wtout, b_out + (size_t)l * 512, x, 512,
            NROWS, nullptr, nullptr, 0);
    }

    rms_kernel<0><<<NROWS, 256, 0, stream>>>(x, final_w, x, 0);
}

// Round 8
// 2623.471 us; speedup vs baseline: 1.1961x; 1.1961x over previous
//
#include <hip/hip_runtime.h>
#include <hip/hip_bf16.h>
#include <math.h>

typedef __attribute__((ext_vector_type(8))) short short8;
typedef __attribute__((ext_vector_type(4))) float f32x4;
typedef __hip_bfloat16 bf16;

#define BB 2
#define TT 16
#define SSQ 257
#define DIMD 512
#define NROWS 8224          // B*T*S ( = 514 * 16 exactly)
#define DII 1365
#define DI2 2730
#define GLUK 1408           // glu K (44*32); kq8 = 176
#define SKP 288             // padded key count for space attn
#define EPSR 1.1920929e-07f

// Fragment-major packed layout: X_pk[t16][kq][l16][8] (shorts): frag load at
// (t16, kt) is lane-linear: base + ((t16*kq8 + kt*4)*128 + lane*8).

__device__ __forceinline__ short f2bfs(float x) {
    bf16 h = __float2bfloat16(x);
    return *reinterpret_cast<short*>(&h);
}

__device__ __forceinline__ size_t pk_idx(int row, int col, int kq8) {
    return ((size_t)((row >> 4) * kq8 + (col >> 3)) * 16 + (row & 15)) * 8 + (col & 7);
}

// ---------------- batched per-layer weight transpose fp32->bf16, packed ----------------
__global__ void wtrans_layer(const float* __restrict__ wq, const float* __restrict__ wk,
                             const float* __restrict__ wv, const float* __restrict__ wo,
                             const float* __restrict__ win, const float* __restrict__ wout,
                             bf16* __restrict__ dqkv, bf16* __restrict__ dwo,
                             bf16* __restrict__ dwin, bf16* __restrict__ dwout) {
    __shared__ float tile[32][33];
    int bid = blockIdx.x;
    const float* src; bf16* dst; int K, M, Kpad, interleave = 0, local, nbase = 0;
    if (bid < 512)       { src = wq;   dst = dqkv; K = 512;  M = 1024; Kpad = 512;  local = bid; }
    else if (bid < 768)  { src = wk;   dst = dqkv; K = 512;  M = 512;  Kpad = 512;  local = bid - 512;  nbase = 1024; }
    else if (bid < 1024) { src = wv;   dst = dqkv; K = 512;  M = 512;  Kpad = 512;  local = bid - 768;  nbase = 1536; }
    else if (bid < 1536) { src = wo;   dst = dwo;  K = 1024; M = 512;  Kpad = 1024; local = bid - 1024; }
    else if (bid < 2944) { src = win;  dst = dwin; K = 512;  M = 2730; Kpad = 512;  local = bid - 1536; interleave = 1; }
    else                 { src = wout; dst = dwout;K = 1365; M = 512;  Kpad = 1408; local = bid - 2944; }
    int tilesx = Kpad >> 5;
    int k0 = (local % tilesx) * 32, m0 = (local / tilesx) * 32;
    int tx = threadIdx.x & 31, ty = threadIdx.x >> 5;
    #pragma unroll
    for (int i = 0; i < 4; ++i) {
        int k = k0 + ty + 8 * i, m = m0 + tx;
        tile[ty + 8 * i][tx] = (k < K && m < M) ? src[(size_t)k * M + m] : 0.f;
    }
    __syncthreads();
    #pragma unroll
    for (int i = 0; i < 4; ++i) {
        int n = m0 + ty + 8 * i, k = k0 + tx;
        int nd = n;
        if (interleave) nd = (n < DII) ? 2 * n : ((n < DI2) ? 2 * (n - DII) + 1 : n);
        nd += nbase;
        dst[pk_idx(nd, k, Kpad >> 3)] = __float2bfloat16(tile[tx][ty + 8 * i]);
    }
}

// ---------------- RMSNorm (optional permuted read); bf16 out packed kq8=64 ----------------
template<int BF16OUT>
__global__ void rms_kernel(const float* __restrict__ x, const float* __restrict__ w,
                           void* __restrict__ out, int perm) {
    int r = blockIdx.x;
    int src = r;
    if (perm) {
        int t = r & 15; int rs = r >> 4; int s = rs % SSQ; int b = rs / SSQ;
        src = (b * TT + t) * SSQ + s;
    }
    const float* xr = x + (size_t)src * DIMD;
    int tid = threadIdx.x;
    float v0 = xr[tid], v1 = xr[tid + 256];
    __shared__ float red[256];
    red[tid] = v0 * v0 + v1 * v1;
    __syncthreads();
    for (int st = 128; st; st >>= 1) {
        if (tid < st) red[tid] += red[tid + st];
        __syncthreads();
    }
    float sc = rsqrtf(red[0] * (1.f / DIMD) + EPSR);
    if (BF16OUT) {
        bf16* o = (bf16*)out;
        o[pk_idx(r, tid, 64)]       = __float2bfloat16(v0 * sc * w[tid]);
        o[pk_idx(r, tid + 256, 64)] = __float2bfloat16(v1 * sc * w[tid + 256]);
    } else {
        float* o = (float*)out + (size_t)r * DIMD;
        o[tid] = v0 * sc * w[tid];
        o[tid + 256] = v1 * sc * w[tid + 256];
    }
}

// ---------------- MFMA bf16 GEMM, no LDS / no barriers, K templated ----------------
// Fully-unrolled K-loop, 2-stage register ping-pong (the 3-stage variant
// collapsed under register pressure in R6; the natural block order has the
// right temporal L2 locality — no swizzle). EPI: 1 = qkv + fused
// l2norm/gamma/rotary; 2 = glu packed out (tanh-gelu); 3 = fp32 accumulate.
template<int EPI, int PERM, int TM, int K>
__global__ __launch_bounds__(256, 2)
void mfma_gemm(const short* __restrict__ Apk, const short* __restrict__ Bpk,
               const float* __restrict__ bias, void* __restrict__ C, int ldc,
               int nrow,
               const float* __restrict__ qg, const float* __restrict__ kg, int rotary) {
    constexpr int MI = TM / 32;
    constexpr int nk = K / 32;
    constexpr int kq8 = K / 8;
    int tid = threadIdx.x;
    int wave = tid >> 6, lane = tid & 63;
    int quad = lane >> 4, l16 = lane & 15;
    int m0 = blockIdx.y * TM, n0 = blockIdx.x * 128;
    int wm = (wave & 1) * (TM / 2), wn = (wave >> 1) * 64;
    int mt0 = (m0 + wm) >> 4, nt0 = (n0 + wn) >> 4;

    const short* ab[MI]; const short* bb[4];
    #pragma unroll
    for (int mi = 0; mi < MI; ++mi) ab[mi] = Apk + (size_t)(mt0 + mi) * kq8 * 128 + lane * 8;
    #pragma unroll
    for (int nj = 0; nj < 4; ++nj)  bb[nj] = Bpk + (size_t)(nt0 + nj) * kq8 * 128 + lane * 8;

    f32x4 zero4 = {0.f, 0.f, 0.f, 0.f};
    f32x4 acc[MI][4];
    #pragma unroll
    for (int i = 0; i < MI; ++i)
        #pragma unroll
        for (int j = 0; j < 4; ++j) acc[i][j] = zero4;

    short8 a0[MI], a1[MI], b0[4], b1[4];
    #pragma unroll
    for (int mi = 0; mi < MI; ++mi) a0[mi] = *(const short8*)(ab[mi]);
    #pragma unroll
    for (int nj = 0; nj < 4; ++nj)  b0[nj] = *(const short8*)(bb[nj]);

    #pragma unroll
    for (int kt = 0; kt < nk; kt += 2) {
        #pragma unroll
        for (int mi = 0; mi < MI; ++mi) a1[mi] = *(const short8*)(ab[mi] + (size_t)(kt + 1) * 512);
        #pragma unroll
        for (int nj = 0; nj < 4; ++nj)  b1[nj] = *(const short8*)(bb[nj] + (size_t)(kt + 1) * 512);
        #pragma unroll
        for (int mi = 0; mi < MI; ++mi)
            #pragma unroll
            for (int nj = 0; nj < 4; ++nj)
                acc[mi][nj] = __builtin_amdgcn_mfma_f32_16x16x32_bf16(
                    a0[mi], b0[nj], acc[mi][nj], 0, 0, 0);
        if (kt + 2 < nk) {
            #pragma unroll
            for (int mi = 0; mi < MI; ++mi) a0[mi] = *(const short8*)(ab[mi] + (size_t)(kt + 2) * 512);
            #pragma unroll
            for (int nj = 0; nj < 4; ++nj)  b0[nj] = *(const short8*)(bb[nj] + (size_t)(kt + 2) * 512);
        }
        #pragma unroll
        for (int mi = 0; mi < MI; ++mi)
            #pragma unroll
            for (int nj = 0; nj < 4; ++nj)
                acc[mi][nj] = __builtin_amdgcn_mfma_f32_16x16x32_bf16(
                    a1[mi], b1[nj], acc[mi][nj], 0, 0, 0);
    }

    if constexpr (EPI == 1) {
        // qkv output: cols wn..wn+63 = exactly one head.
        int head = (n0 + wn) >> 6;          // 0..15 q, 16..23 k, 24..31 v
        float gl0 = 0.f, gl1 = 0.f, gl2 = 0.f, gl3 = 0.f, inv0 = 0.f, inv1 = 0.f;
        if (head < 24) {
            const float* g = head < 16 ? qg + head * 64 : kg + (head - 16) * 64;
            gl0 = (g[l16] + 1.f) * 8.f;
            gl1 = (g[16 + l16] + 1.f) * 8.f;
            gl2 = (g[32 + l16] + 1.f) * 8.f;
            gl3 = (g[48 + l16] + 1.f) * 8.f;
            if (rotary) {
                inv0 = __expf(-(float)l16 * 0.28782313662425572f);        // ln(1e4)/32
                inv1 = __expf(-(float)(l16 + 16) * 0.28782313662425572f);
            }
        }
        #pragma unroll
        for (int mi = 0; mi < MI; ++mi) {
            #pragma unroll
            for (int e = 0; e < 4; ++e) {
                int row = m0 + wm + mi * 16 + quad * 4 + e;
                float v0 = acc[mi][0][e], v1 = acc[mi][1][e];
                float v2 = acc[mi][2][e], v3 = acc[mi][3][e];
                if (head < 24) {
                    float ss = v0 * v0 + v1 * v1 + v2 * v2 + v3 * v3;
                    ss += __shfl_xor(ss, 1); ss += __shfl_xor(ss, 2);
                    ss += __shfl_xor(ss, 4); ss += __shfl_xor(ss, 8);
                    float invn = 1.f / fmaxf(sqrtf(ss), 1e-12f);
                    v0 *= invn * gl0; v1 *= invn * gl1;
                    v2 *= invn * gl2; v3 *= invn * gl3;
                    if (rotary) {
                        float tt = (float)(row & 15);
                        float a0v = tt * inv0, a1v = tt * inv1;
                        float c0 = __cosf(a0v), s0 = __sinf(a0v);
                        float c1 = __cosf(a1v), s1 = __sinf(a1v);
                        float n0v = v0 * c0 - v2 * s0;
                        float n1v = v1 * c1 - v3 * s1;
                        float n2v = v2 * c0 + v0 * s0;
                        float n3v = v3 * c1 + v1 * s1;
                        v0 = n0v; v1 = n1v; v2 = n2v; v3 = n3v;
                    }
                }
                if (row < nrow) {
                    bf16* p = (bf16*)C + (size_t)row * ldc + n0 + wn + l16;
                    p[0]  = __float2bfloat16(v0);
                    p[16] = __float2bfloat16(v1);
                    p[32] = __float2bfloat16(v2);
                    p[48] = __float2bfloat16(v3);
                }
            }
        }
    } else if constexpr (EPI == 2) {
        // interleaved a/g; tanh-form gelu; write packed glu (kq8=176) at j=col/2.
        #pragma unroll
        for (int mi = 0; mi < MI; ++mi) {
            #pragma unroll
            for (int e = 0; e < 4; ++e) {
                int row = m0 + wm + mi * 16 + quad * 4 + e;
                #pragma unroll
                for (int nj = 0; nj < 4; ++nj) {
                    int col = n0 + wn + nj * 16 + l16;
                    int j = col >> 1;
                    float b = (j < DII) ? ((col & 1) ? bias[DII + j] : bias[j]) : 0.f;
                    float v = acc[mi][nj][e] + b;
                    float prt = __shfl_xor(v, 1);
                    if (!(l16 & 1) && row < nrow) {
                        float gv = prt;
                        float u = 0.7978845608028654f * (gv + 0.044715f * gv * gv * gv);
                        float e2u = __expf(2.f * u);
                        float th = 1.f - 2.f * __builtin_amdgcn_rcpf(e2u + 1.f);
                        float glu = v * 0.5f * gv * (1.f + th);
                        ((bf16*)C)[pk_idx(row, j, 176)] = __float2bfloat16(glu);
                    }
                }
            }
        }
    } else {
        #pragma unroll
        for (int mi = 0; mi < MI; ++mi) {
            #pragma unroll
            for (int e = 0; e < 4; ++e) {
                int row = m0 + wm + mi * 16 + quad * 4 + e;
                if (row >= nrow) continue;
                int orow = row;
                if (PERM) {
                    int tt = row & 15; int rs = row >> 4; int s = rs % SSQ; int b = rs / SSQ;
                    orow = (b * TT + tt) * SSQ + s;
                }
                #pragma unroll
                for (int nj = 0; nj < 4; ++nj) {
                    int col = n0 + wn + nj * 16 + l16;
                    float v = acc[mi][nj][e];
                    if (bias) v += bias[col];
                    ((float*)C)[(size_t)orow * ldc + col] += v;
                }
            }
        }
    }
}

// ---------------- V transpose via LDS tile: vt[bt*8+kh][64][SKP] bf16 ----------------
// grid 256 = (bt,kh); coalesced reads (128B/key-row) and 64B-chunk writes.
__global__ void vtrans_kernel(const bf16* __restrict__ qkv, bf16* __restrict__ vt) {
    __shared__ bf16 tile[32][72];
    int bkh = blockIdx.x;          // bt*8 + kh
    int bt = bkh >> 3, kh = bkh & 7;
    int tid = threadIdx.x;
    bf16* vb = vt + (size_t)bkh * 64 * SKP;
    for (int kc = 0; kc < 9; ++kc) {
        #pragma unroll
        for (int i = 0; i < 8; ++i) {
            int idx = tid + 256 * i;   // 0..2047 = 32 keys x 64 d
            int kl = idx >> 6, d = idx & 63;
            int key = kc * 32 + kl;
            bf16 v = __float2bfloat16(0.f);
            if (key < SSQ)
                v = qkv[((size_t)(bt * SSQ + key)) * 2048 + 1536 + kh * 64 + d];
            tile[kl][d] = v;
        }
        __syncthreads();
        #pragma unroll
        for (int i = 0; i < 8; ++i) {
            int idx = tid + 256 * i;   // 64 d x 32 keys
            int dl = idx >> 5, kl = idx & 31;
            vb[(size_t)dl * SKP + kc * 32 + kl] = tile[kl][dl];
        }
        __syncthreads();
    }
}

// ---------------- space attention: S^T in registers, zero LDS; ob packed out ----------------
__global__ __launch_bounds__(256)
void space_attn_kernel(const bf16* __restrict__ qkv, const bf16* __restrict__ vt,
                       bf16* __restrict__ obpk) {
    int qt = blockIdx.x, qh = blockIdx.y, bt = blockIdx.z;
    int kh = qh >> 1;
    int tid = threadIdx.x, wave = tid >> 6, lane = tid & 63;
    int quad = lane >> 4, l16 = lane & 15;
    int q0w = qt * 64 + wave * 16;
    int q = q0w + l16;
    int qc = q > 256 ? 256 : q;
    const short* qbase = (const short*)qkv + (size_t)bt * SSQ * 2048;
    const short* qp = qbase + (size_t)qc * 2048 + qh * 64;
    short8 bq0 = *(const short8*)(qp + quad * 8);
    short8 bq1 = *(const short8*)(qp + 32 + quad * 8);
    f32x4 zero4 = {0.f, 0.f, 0.f, 0.f};
    f32x4 sc[18];

    #pragma unroll
    for (int kt = 0; kt < 17; ++kt) {
        int keyl = kt * 16 + l16; if (keyl > 256) keyl = 256;
        const short* kp = qbase + (size_t)keyl * 2048 + 1024 + kh * 64;
        short8 ak0 = *(const short8*)(kp + quad * 8);
        short8 ak1 = *(const short8*)(kp + 32 + quad * 8);
        f32x4 c = zero4;
        c = __builtin_amdgcn_mfma_f32_16x16x32_bf16(ak0, bq0, c, 0, 0, 0);
        c = __builtin_amdgcn_mfma_f32_16x16x32_bf16(ak1, bq1, c, 0, 0, 0);
        #pragma unroll
        for (int e = 0; e < 4; ++e) {
            float e2x = __expf(c[e] * 0.005f);
            float v = 50.f - 100.f * __builtin_amdgcn_rcpf(e2x + 1.f);
            if (kt == 16) {
                bool valid = (e == 0) && (quad == 0) && (q == 256);
                v = valid ? v : -1e30f;
            }
            c[e] = v;
        }
        sc[kt] = c;
    }

    float mx = -1e30f;
    #pragma unroll
    for (int kt = 0; kt < 17; ++kt)
        mx = fmaxf(mx, fmaxf(fmaxf(sc[kt][0], sc[kt][1]), fmaxf(sc[kt][2], sc[kt][3])));
    mx = fmaxf(mx, __shfl_xor(mx, 16));
    mx = fmaxf(mx, __shfl_xor(mx, 32));
    float sum = 0.f;
    #pragma unroll
    for (int kt = 0; kt < 17; ++kt) {
        #pragma unroll
        for (int e = 0; e < 4; ++e) {
            float p = __expf(sc[kt][e] - mx);
            sc[kt][e] = p;
            sum += p;
        }
    }
    #pragma unroll
    for (int e = 0; e < 4; ++e) sc[17][e] = 0.f;
    sum += __shfl_xor(sum, 16);
    sum += __shfl_xor(sum, 32);
    float inv = __builtin_amdgcn_rcpf(sum);
    f32x4 inv4;
    #pragma unroll
    for (int e = 0; e < 4; ++e) inv4[e] = __shfl(inv, quad * 4 + e);

    f32x4 oacc[4];
    #pragma unroll
    for (int nt = 0; nt < 4; ++nt) oacc[nt] = zero4;
    const short* vbp = (const short*)vt + ((size_t)(bt * 8 + kh) * 64 + l16) * SKP;
    #pragma unroll
    for (int c8 = 0; c8 < 9; ++c8) {
        short8 pb;
        #pragma unroll
        for (int j = 0; j < 8; ++j) {
            int src_lane = ((quad & 1) * 2 + (j >> 2)) * 16 + l16;
            float v0 = __shfl(sc[2 * c8][j & 3], src_lane);
            float v1 = __shfl(sc[2 * c8 + 1][j & 3], src_lane);
            pb[j] = f2bfs(quad < 2 ? v0 : v1);
        }
        #pragma unroll
        for (int nt = 0; nt < 4; ++nt) {
            short8 av = *(const short8*)(vbp + (size_t)(nt * 16) * SKP + c8 * 32 + quad * 8);
            oacc[nt] = __builtin_amdgcn_mfma_f32_16x16x32_bf16(pb, av, oacc[nt], 0, 0, 0);
        }
    }

    #pragma unroll
    for (int e = 0; e < 4; ++e) {
        int qq = q0w + quad * 4 + e;
        if (qq <= 256) {
            int row = bt * SSQ + qq;
            float s = inv4[e];
            #pragma unroll
            for (int nt = 0; nt < 4; ++nt)
                obpk[pk_idx(row, qh * 64 + nt * 16 + l16, 128)] =
                    __float2bfloat16(oacc[nt][e] * s);
        }
    }
}

// ---------------- time attention (n=16, causal): one block per (b*s, qh) ----------------
__global__ void time_attn_kernel(const bf16* __restrict__ qkv, bf16* __restrict__ obpk) {
    __shared__ float qs[16][65], ks[16][65], ps[16][17];
    int bs = blockIdx.x, qh = blockIdx.y, kh = qh >> 1;
    int tid = threadIdx.x;
    size_t rowbase = (size_t)bs * 16;
    #pragma unroll
    for (int i = 0; i < 4; ++i) {
        int idx = tid + 256 * i;
        int r = idx >> 6, d = idx & 63;
        qs[r][d] = __bfloat162float(qkv[(rowbase + r) * 2048 + qh * 64 + d]);
        ks[r][d] = __bfloat162float(qkv[(rowbase + r) * 2048 + 1024 + kh * 64 + d]);
    }
    __syncthreads();
    int i = tid >> 4, j = tid & 15;
    float dot = 0.f;
    #pragma unroll 16
    for (int d = 0; d < 64; ++d) dot += qs[i][d] * ks[j][d];
    float s = dot * 0.125f;
    float ex = __expf(s * 0.04f);
    s = 50.f * (ex - 1.f) / (ex + 1.f);
    if (j > i) s = -1e30f;
    float mx = s;
    mx = fmaxf(mx, __shfl_xor(mx, 1));
    mx = fmaxf(mx, __shfl_xor(mx, 2));
    mx = fmaxf(mx, __shfl_xor(mx, 4));
    mx = fmaxf(mx, __shfl_xor(mx, 8));
    float p = __expf(s - mx);
    float sum = p;
    sum += __shfl_xor(sum, 1);
    sum += __shfl_xor(sum, 2);
    sum += __shfl_xor(sum, 4);
    sum += __shfl_xor(sum, 8);
    ps[i][j] = p / sum;
    __syncthreads();
    #pragma unroll
    for (int ii = 0; ii < 4; ++ii) {
        int idx = tid + 256 * ii;
        int r = idx >> 6, d = idx & 63;
        float acc = 0.f;
        #pragma unroll
        for (int jj = 0; jj < 16; ++jj)
            acc += ps[r][jj] * __bfloat162float(qkv[(rowbase + jj) * 2048 + 1536 + kh * 64 + d]);
        obpk[pk_idx((int)(rowbase + r), qh * 64 + d, 128)] = __float2bfloat16(acc);
    }
}

// ---------------- host-side launch ----------------
extern "C" void kernel_launch(void* const* d_in, const int* in_sizes, int n_in,
                              void* d_out, int out_size, void* d_ws, size_t ws_size,
                              hipStream_t stream) {
    const float* tokens      = (const float*)d_in[0];
    const float* attn_norm_w = (const float*)d_in[1];
    const float* Wq          = (const float*)d_in[2];
    const float* Wk          = (const float*)d_in[3];
    const float* Wv          = (const float*)d_in[4];
    const float* q_gamma     = (const float*)d_in[5];
    const float* k_gamma     = (const float*)d_in[6];
    const float* Wo          = (const float*)d_in[7];
    const float* ff_norm_w   = (const float*)d_in[8];
    const float* W_in        = (const float*)d_in[9];
    const float* b_in        = (const float*)d_in[10];
    const float* W_out       = (const float*)d_in[11];
    const float* b_out       = (const float*)d_in[12];
    const float* final_w     = (const float*)d_in[13];

    float* x = (float*)d_out;
    char* ws = (char*)d_ws;

    // packed per-layer weights (reused each layer)
    bf16* wtqkv = (bf16*)ws;                                  // N=2048, kq8=64:  2 MB
    bf16* wto   = (bf16*)(ws + 2097152);                      // N=512,  kq8=128: 1 MB
    bf16* wtin  = (bf16*)(ws + 2097152 + 1048576);            // N=2816, kq8=64:  2.9 MB
    bf16* wtout = (bf16*)(ws + 2097152 + 1048576 + 2883584);  // N=512,  kq8=176: 1.4 MB
    size_t off = 2097152 + 1048576 + 2883584 + 1441792;
    bf16* h_pk  = (bf16*)(ws + off);   off += (size_t)520 * 64 * 128 * 2;    // 8.5 MB
    bf16* ob_pk = (bf16*)(ws + off);   off += (size_t)520 * 128 * 128 * 2;   // 17 MB
    bf16* qkv   = (bf16*)(ws + off);                                          // 33.7 MB
    bf16* glu_pk= (bf16*)(ws + off);   off += (size_t)NROWS * 2048 * 2;      // (alias)
    bf16* vt    = (bf16*)(ws + off);                                          // 9.4 MB

    hipMemcpyAsync(x, tokens, (size_t)NROWS * 512 * 4, hipMemcpyDeviceToDevice, stream);

    for (int l = 0; l < 8; ++l) {
        int is_time = ((l + 1) % 4 == 0) ? 1 : 0;
        wtrans_layer<<<3648, 256, 0, stream>>>(
            Wq + (size_t)l * 512 * 1024, Wk + (size_t)l * 512 * 512,
            Wv + (size_t)l * 512 * 512, Wo + (size_t)l * 1024 * 512,
            W_in + (size_t)l * 512 * DI2, W_out + (size_t)l * DII * 512,
            wtqkv, wto, wtin, wtout);

        // ---- attention block ----
        rms_kernel<1><<<NROWS, 256, 0, stream>>>(x, attn_norm_w + (size_t)l * 512, h_pk, is_time);
        mfma_gemm<1, 0, 128, 512><<<dim3(16, 65), 256, 0, stream>>>(
            (const short*)h_pk, (const short*)wtqkv, nullptr, qkv, 2048, NROWS,
            q_gamma + (size_t)l * 1024, k_gamma + (size_t)l * 512, is_time);
        if (is_time) {
            time_attn_kernel<<<dim3(514, 16), 256, 0, stream>>>(qkv, ob_pk);
            mfma_gemm<3, 1, 64, 1024><<<dim3(4, 129), 256, 0, stream>>>(
                (const short*)ob_pk, (const short*)wto, nullptr, x, 512, NROWS,
                nullptr, nullptr, 0);
        } else {
            vtrans_kernel<<<256, 256, 0, stream>>>(qkv, vt);
            space_attn_kernel<<<dim3(5, 16, 32), 256, 0, stream>>>(qkv, vt, ob_pk);
            mfma_gemm<3, 0, 64, 1024><<<dim3(4, 129), 256, 0, stream>>>(
                (const short*)ob_pk, (const short*)wto, nullptr, x, 512, NROWS,
                nullptr, nullptr, 0);
        }

        // ---- feed-forward block ----
        rms_kernel<1><<<NROWS, 256, 0, stream>>>(x, ff_norm_w + (size_t)l * 512, h_pk, 0);
        mfma_gemm<2, 0, 128, 512><<<dim3(22, 65), 256, 0, stream>>>(
            (const short*)h_pk, (const short*)wtin, b_in + (size_t)l * DI2, glu_pk, 0,
            NROWS, nullptr, nullptr, 0);
        mfma_gemm<3, 0, 64, GLUK><<<dim3(4, 129), 256, 0, stream>>>(
            (const short*)glu_pk, (const short*)wtout, b_out + (size_t)l * 512, x, 512,
            NROWS, nullptr, nullptr, 0);
    }

    rms_kernel<0><<<NROWS, 256, 0, stream>>>(x, final_w, x, 0);
}

// Round 9
// 2623.433 us; speedup vs baseline: 1.1961x; 1.0000x over previous
//
#include <hip/hip_runtime.h>
#include <hip/hip_bf16.h>
#include <math.h>

typedef __attribute__((ext_vector_type(8))) short short8;
typedef __attribute__((ext_vector_type(4))) float f32x4;
typedef __hip_bfloat16 bf16;

#define BB 2
#define TT 16
#define SSQ 257
#define DIMD 512
#define NROWS 8224          // B*T*S ( = 514 * 16 exactly)
#define DII 1365
#define DI2 2730
#define GLUK 1408           // glu K (44*32); kq8 = 176
#define SKP 288             // padded key count for space attn
#define EPSR 1.1920929e-07f

// Fragment-major packed layout: X_pk[t16][kq][l16][8] (shorts): frag load at
// (t16, kt) is lane-linear: base + ((t16*kq8 + kt*4)*128 + lane*8).

__device__ __forceinline__ short f2bfs(float x) {
    bf16 h = __float2bfloat16(x);
    return *reinterpret_cast<short*>(&h);
}

__device__ __forceinline__ size_t pk_idx(int row, int col, int kq8) {
    return ((size_t)((row >> 4) * kq8 + (col >> 3)) * 16 + (row & 15)) * 8 + (col & 7);
}

// ---------------- batched per-layer weight transpose fp32->bf16, packed ----------------
__global__ void wtrans_layer(const float* __restrict__ wq, const float* __restrict__ wk,
                             const float* __restrict__ wv, const float* __restrict__ wo,
                             const float* __restrict__ win, const float* __restrict__ wout,
                             bf16* __restrict__ dqkv, bf16* __restrict__ dwo,
                             bf16* __restrict__ dwin, bf16* __restrict__ dwout) {
    __shared__ float tile[32][33];
    int bid = blockIdx.x;
    const float* src; bf16* dst; int K, M, Kpad, interleave = 0, local, nbase = 0;
    if (bid < 512)       { src = wq;   dst = dqkv; K = 512;  M = 1024; Kpad = 512;  local = bid; }
    else if (bid < 768)  { src = wk;   dst = dqkv; K = 512;  M = 512;  Kpad = 512;  local = bid - 512;  nbase = 1024; }
    else if (bid < 1024) { src = wv;   dst = dqkv; K = 512;  M = 512;  Kpad = 512;  local = bid - 768;  nbase = 1536; }
    else if (bid < 1536) { src = wo;   dst = dwo;  K = 1024; M = 512;  Kpad = 1024; local = bid - 1024; }
    else if (bid < 2944) { src = win;  dst = dwin; K = 512;  M = 2730; Kpad = 512;  local = bid - 1536; interleave = 1; }
    else                 { src = wout; dst = dwout;K = 1365; M = 512;  Kpad = 1408; local = bid - 2944; }
    int tilesx = Kpad >> 5;
    int k0 = (local % tilesx) * 32, m0 = (local / tilesx) * 32;
    int tx = threadIdx.x & 31, ty = threadIdx.x >> 5;
    #pragma unroll
    for (int i = 0; i < 4; ++i) {
        int k = k0 + ty + 8 * i, m = m0 + tx;
        tile[ty + 8 * i][tx] = (k < K && m < M) ? src[(size_t)k * M + m] : 0.f;
    }
    __syncthreads();
    #pragma unroll
    for (int i = 0; i < 4; ++i) {
        int n = m0 + ty + 8 * i, k = k0 + tx;
        int nd = n;
        if (interleave) nd = (n < DII) ? 2 * n : ((n < DI2) ? 2 * (n - DII) + 1 : n);
        nd += nbase;
        dst[pk_idx(nd, k, Kpad >> 3)] = __float2bfloat16(tile[tx][ty + 8 * i]);
    }
}

// ---------------- RMSNorm (optional permuted read); bf16 out packed kq8=64 ----------------
template<int BF16OUT>
__global__ void rms_kernel(const float* __restrict__ x, const float* __restrict__ w,
                           void* __restrict__ out, int perm) {
    int r = blockIdx.x;
    int src = r;
    if (perm) {
        int t = r & 15; int rs = r >> 4; int s = rs % SSQ; int b = rs / SSQ;
        src = (b * TT + t) * SSQ + s;
    }
    const float* xr = x + (size_t)src * DIMD;
    int tid = threadIdx.x;
    float v0 = xr[tid], v1 = xr[tid + 256];
    __shared__ float red[256];
    red[tid] = v0 * v0 + v1 * v1;
    __syncthreads();
    for (int st = 128; st; st >>= 1) {
        if (tid < st) red[tid] += red[tid + st];
        __syncthreads();
    }
    float sc = rsqrtf(red[0] * (1.f / DIMD) + EPSR);
    if (BF16OUT) {
        bf16* o = (bf16*)out;
        o[pk_idx(r, tid, 64)]       = __float2bfloat16(v0 * sc * w[tid]);
        o[pk_idx(r, tid + 256, 64)] = __float2bfloat16(v1 * sc * w[tid + 256]);
    } else {
        float* o = (float*)out + (size_t)r * DIMD;
        o[tid] = v0 * sc * w[tid];
        o[tid + 256] = v1 * sc * w[tid + 256];
    }
}

// ---------------- MFMA bf16 GEMM, no LDS / no barriers, K templated ----------------
// Fully-unrolled K-loop. Pipeline depth: 2 stages for TM=128 (register-bound),
// 3 stages for TM=64 (MI=2 leaves VGPR room). XCD swizzle: m-tiles partitioned
// across lin%8 groups, n fastest within a group -> per-XCD L2 holds ~3 A-strips
// + full B (<4MB). EPI: 1 = qkv + fused l2norm/gamma/rotary; 2 = glu packed
// out (tanh-gelu); 3 = fp32 accumulate (+bias, opt PERM).
template<int EPI, int PERM, int TM, int K>
__global__ __launch_bounds__(256, 2)
void mfma_gemm(const short* __restrict__ Apk, const short* __restrict__ Bpk,
               const float* __restrict__ bias, void* __restrict__ C, int ldc,
               int nrow,
               const float* __restrict__ qg, const float* __restrict__ kg, int rotary) {
    constexpr int MI = TM / 32;
    constexpr int nk = K / 32;
    constexpr int kq8 = K / 8;
    constexpr int PD = (TM == 64) ? 3 : 2;     // pipeline stages
    int tid = threadIdx.x;
    int wave = tid >> 6, lane = tid & 63;
    int quad = lane >> 4, l16 = lane & 15;

    // XCD-partitioned tile order: group xc owns a contiguous m-tile range,
    // sweeps n fastest within it.
    int gx = gridDim.x;
    int lin = blockIdx.y * gx + blockIdx.x;
    int total = gx * gridDim.y;
    int xc = lin & 7, jj = lin >> 3;
    int per = total >> 3, rem = total & 7;
    int base = xc * per + (xc < rem ? xc : rem);
    int t = base + jj;
    int n0 = (t % gx) * 128;
    int m0 = (t / gx) * TM;

    int wm = (wave & 1) * (TM / 2), wn = (wave >> 1) * 64;
    int mt0 = (m0 + wm) >> 4, nt0 = (n0 + wn) >> 4;

    const short* ab[MI]; const short* bb[4];
    #pragma unroll
    for (int mi = 0; mi < MI; ++mi) ab[mi] = Apk + (size_t)(mt0 + mi) * kq8 * 128 + lane * 8;
    #pragma unroll
    for (int nj = 0; nj < 4; ++nj)  bb[nj] = Bpk + (size_t)(nt0 + nj) * kq8 * 128 + lane * 8;

    f32x4 zero4 = {0.f, 0.f, 0.f, 0.f};
    f32x4 acc[MI][4];
    #pragma unroll
    for (int i = 0; i < MI; ++i)
        #pragma unroll
        for (int j = 0; j < 4; ++j) acc[i][j] = zero4;

    short8 Ab[PD][MI], Bb[PD][4];
    #pragma unroll
    for (int s = 0; s < PD - 1; ++s) {
        #pragma unroll
        for (int mi = 0; mi < MI; ++mi) Ab[s][mi] = *(const short8*)(ab[mi] + (size_t)s * 512);
        #pragma unroll
        for (int nj = 0; nj < 4; ++nj)  Bb[s][nj] = *(const short8*)(bb[nj] + (size_t)s * 512);
    }
    #pragma unroll
    for (int kt = 0; kt < nk; ++kt) {
        if (kt + PD - 1 < nk) {
            const int s = (kt + PD - 1) % PD;
            #pragma unroll
            for (int mi = 0; mi < MI; ++mi) Ab[s][mi] = *(const short8*)(ab[mi] + (size_t)(kt + PD - 1) * 512);
            #pragma unroll
            for (int nj = 0; nj < 4; ++nj)  Bb[s][nj] = *(const short8*)(bb[nj] + (size_t)(kt + PD - 1) * 512);
        }
        const int c = kt % PD;
        #pragma unroll
        for (int mi = 0; mi < MI; ++mi)
            #pragma unroll
            for (int nj = 0; nj < 4; ++nj)
                acc[mi][nj] = __builtin_amdgcn_mfma_f32_16x16x32_bf16(
                    Ab[c][mi], Bb[c][nj], acc[mi][nj], 0, 0, 0);
    }

    if constexpr (EPI == 1) {
        // qkv output: cols wn..wn+63 = exactly one head.
        int head = (n0 + wn) >> 6;          // 0..15 q, 16..23 k, 24..31 v
        float gl0 = 0.f, gl1 = 0.f, gl2 = 0.f, gl3 = 0.f, inv0 = 0.f, inv1 = 0.f;
        if (head < 24) {
            const float* g = head < 16 ? qg + head * 64 : kg + (head - 16) * 64;
            gl0 = (g[l16] + 1.f) * 8.f;
            gl1 = (g[16 + l16] + 1.f) * 8.f;
            gl2 = (g[32 + l16] + 1.f) * 8.f;
            gl3 = (g[48 + l16] + 1.f) * 8.f;
            if (rotary) {
                inv0 = __expf(-(float)l16 * 0.28782313662425572f);        // ln(1e4)/32
                inv1 = __expf(-(float)(l16 + 16) * 0.28782313662425572f);
            }
        }
        #pragma unroll
        for (int mi = 0; mi < MI; ++mi) {
            #pragma unroll
            for (int e = 0; e < 4; ++e) {
                int row = m0 + wm + mi * 16 + quad * 4 + e;
                float v0 = acc[mi][0][e], v1 = acc[mi][1][e];
                float v2 = acc[mi][2][e], v3 = acc[mi][3][e];
                if (head < 24) {
                    float ss = v0 * v0 + v1 * v1 + v2 * v2 + v3 * v3;
                    ss += __shfl_xor(ss, 1); ss += __shfl_xor(ss, 2);
                    ss += __shfl_xor(ss, 4); ss += __shfl_xor(ss, 8);
                    float invn = 1.f / fmaxf(sqrtf(ss), 1e-12f);
                    v0 *= invn * gl0; v1 *= invn * gl1;
                    v2 *= invn * gl2; v3 *= invn * gl3;
                    if (rotary) {
                        float tt = (float)(row & 15);
                        float a0v = tt * inv0, a1v = tt * inv1;
                        float c0 = __cosf(a0v), s0 = __sinf(a0v);
                        float c1 = __cosf(a1v), s1 = __sinf(a1v);
                        float n0v = v0 * c0 - v2 * s0;
                        float n1v = v1 * c1 - v3 * s1;
                        float n2v = v2 * c0 + v0 * s0;
                        float n3v = v3 * c1 + v1 * s1;
                        v0 = n0v; v1 = n1v; v2 = n2v; v3 = n3v;
                    }
                }
                if (row < nrow) {
                    bf16* p = (bf16*)C + (size_t)row * ldc + n0 + wn + l16;
                    p[0]  = __float2bfloat16(v0);
                    p[16] = __float2bfloat16(v1);
                    p[32] = __float2bfloat16(v2);
                    p[48] = __float2bfloat16(v3);
                }
            }
        }
    } else if constexpr (EPI == 2) {
        // interleaved a/g; tanh-form gelu; write packed glu (kq8=176) at j=col/2.
        #pragma unroll
        for (int mi = 0; mi < MI; ++mi) {
            #pragma unroll
            for (int e = 0; e < 4; ++e) {
                int row = m0 + wm + mi * 16 + quad * 4 + e;
                #pragma unroll
                for (int nj = 0; nj < 4; ++nj) {
                    int col = n0 + wn + nj * 16 + l16;
                    int j = col >> 1;
                    float b = (j < DII) ? ((col & 1) ? bias[DII + j] : bias[j]) : 0.f;
                    float v = acc[mi][nj][e] + b;
                    float prt = __shfl_xor(v, 1);
                    if (!(l16 & 1) && row < nrow) {
                        float gv = prt;
                        float u = 0.7978845608028654f * (gv + 0.044715f * gv * gv * gv);
                        float e2u = __expf(2.f * u);
                        float th = 1.f - 2.f * __builtin_amdgcn_rcpf(e2u + 1.f);
                        float glu = v * 0.5f * gv * (1.f + th);
                        ((bf16*)C)[pk_idx(row, j, 176)] = __float2bfloat16(glu);
                    }
                }
            }
        }
    } else {
        #pragma unroll
        for (int mi = 0; mi < MI; ++mi) {
            #pragma unroll
            for (int e = 0; e < 4; ++e) {
                int row = m0 + wm + mi * 16 + quad * 4 + e;
                if (row >= nrow) continue;
                int orow = row;
                if (PERM) {
                    int tt = row & 15; int rs = row >> 4; int s = rs % SSQ; int b = rs / SSQ;
                    orow = (b * TT + tt) * SSQ + s;
                }
                #pragma unroll
                for (int nj = 0; nj < 4; ++nj) {
                    int col = n0 + wn + nj * 16 + l16;
                    float v = acc[mi][nj][e];
                    if (bias) v += bias[col];
                    ((float*)C)[(size_t)orow * ldc + col] += v;
                }
            }
        }
    }
}

// ---------------- V transpose via LDS tile: vt[bt*8+kh][64][SKP] bf16 ----------------
__global__ void vtrans_kernel(const bf16* __restrict__ qkv, bf16* __restrict__ vt) {
    __shared__ bf16 tile[32][72];
    int bkh = blockIdx.x;          // bt*8 + kh
    int bt = bkh >> 3, kh = bkh & 7;
    int tid = threadIdx.x;
    bf16* vb = vt + (size_t)bkh * 64 * SKP;
    for (int kc = 0; kc < 9; ++kc) {
        #pragma unroll
        for (int i = 0; i < 8; ++i) {
            int idx = tid + 256 * i;   // 0..2047 = 32 keys x 64 d
            int kl = idx >> 6, d = idx & 63;
            int key = kc * 32 + kl;
            bf16 v = __float2bfloat16(0.f);
            if (key < SSQ)
                v = qkv[((size_t)(bt * SSQ + key)) * 2048 + 1536 + kh * 64 + d];
            tile[kl][d] = v;
        }
        __syncthreads();
        #pragma unroll
        for (int i = 0; i < 8; ++i) {
            int idx = tid + 256 * i;   // 64 d x 32 keys
            int dl = idx >> 5, kl = idx & 31;
            vb[(size_t)dl * SKP + kc * 32 + kl] = tile[kl][dl];
        }
        __syncthreads();
    }
}

// ---------------- space attention: S^T in registers, zero LDS; ob packed out ----------------
__global__ __launch_bounds__(256)
void space_attn_kernel(const bf16* __restrict__ qkv, const bf16* __restrict__ vt,
                       bf16* __restrict__ obpk) {
    int qt = blockIdx.x, qh = blockIdx.y, bt = blockIdx.z;
    int kh = qh >> 1;
    int tid = threadIdx.x, wave = tid >> 6, lane = tid & 63;
    int quad = lane >> 4, l16 = lane & 15;
    int q0w = qt * 64 + wave * 16;
    int q = q0w + l16;
    int qc = q > 256 ? 256 : q;
    const short* qbase = (const short*)qkv + (size_t)bt * SSQ * 2048;
    const short* qp = qbase + (size_t)qc * 2048 + qh * 64;
    short8 bq0 = *(const short8*)(qp + quad * 8);
    short8 bq1 = *(const short8*)(qp + 32 + quad * 8);
    f32x4 zero4 = {0.f, 0.f, 0.f, 0.f};
    f32x4 sc[18];

    #pragma unroll
    for (int kt = 0; kt < 17; ++kt) {
        int keyl = kt * 16 + l16; if (keyl > 256) keyl = 256;
        const short* kp = qbase + (size_t)keyl * 2048 + 1024 + kh * 64;
        short8 ak0 = *(const short8*)(kp + quad * 8);
        short8 ak1 = *(const short8*)(kp + 32 + quad * 8);
        f32x4 c = zero4;
        c = __builtin_amdgcn_mfma_f32_16x16x32_bf16(ak0, bq0, c, 0, 0, 0);
        c = __builtin_amdgcn_mfma_f32_16x16x32_bf16(ak1, bq1, c, 0, 0, 0);
        #pragma unroll
        for (int e = 0; e < 4; ++e) {
            float e2x = __expf(c[e] * 0.005f);
            float v = 50.f - 100.f * __builtin_amdgcn_rcpf(e2x + 1.f);
            if (kt == 16) {
                bool valid = (e == 0) && (quad == 0) && (q == 256);
                v = valid ? v : -1e30f;
            }
            c[e] = v;
        }
        sc[kt] = c;
    }

    float mx = -1e30f;
    #pragma unroll
    for (int kt = 0; kt < 17; ++kt)
        mx = fmaxf(mx, fmaxf(fmaxf(sc[kt][0], sc[kt][1]), fmaxf(sc[kt][2], sc[kt][3])));
    mx = fmaxf(mx, __shfl_xor(mx, 16));
    mx = fmaxf(mx, __shfl_xor(mx, 32));
    float sum = 0.f;
    #pragma unroll
    for (int kt = 0; kt < 17; ++kt) {
        #pragma unroll
        for (int e = 0; e < 4; ++e) {
            float p = __expf(sc[kt][e] - mx);
            sc[kt][e] = p;
            sum += p;
        }
    }
    #pragma unroll
    for (int e = 0; e < 4; ++e) sc[17][e] = 0.f;
    sum += __shfl_xor(sum, 16);
    sum += __shfl_xor(sum, 32);
    float inv = __builtin_amdgcn_rcpf(sum);
    f32x4 inv4;
    #pragma unroll
    for (int e = 0; e < 4; ++e) inv4[e] = __shfl(inv, quad * 4 + e);

    f32x4 oacc[4];
    #pragma unroll
    for (int nt = 0; nt < 4; ++nt) oacc[nt] = zero4;
    const short* vbp = (const short*)vt + ((size_t)(bt * 8 + kh) * 64 + l16) * SKP;
    #pragma unroll
    for (int c8 = 0; c8 < 9; ++c8) {
        short8 pb;
        #pragma unroll
        for (int j = 0; j < 8; ++j) {
            int src_lane = ((quad & 1) * 2 + (j >> 2)) * 16 + l16;
            float v0 = __shfl(sc[2 * c8][j & 3], src_lane);
            float v1 = __shfl(sc[2 * c8 + 1][j & 3], src_lane);
            pb[j] = f2bfs(quad < 2 ? v0 : v1);
        }
        #pragma unroll
        for (int nt = 0; nt < 4; ++nt) {
            short8 av = *(const short8*)(vbp + (size_t)(nt * 16) * SKP + c8 * 32 + quad * 8);
            oacc[nt] = __builtin_amdgcn_mfma_f32_16x16x32_bf16(pb, av, oacc[nt], 0, 0, 0);
        }
    }

    #pragma unroll
    for (int e = 0; e < 4; ++e) {
        int qq = q0w + quad * 4 + e;
        if (qq <= 256) {
            int row = bt * SSQ + qq;
            float s = inv4[e];
            #pragma unroll
            for (int nt = 0; nt < 4; ++nt)
                obpk[pk_idx(row, qh * 64 + nt * 16 + l16, 128)] =
                    __float2bfloat16(oacc[nt][e] * s);
        }
    }
}

// ---------------- time attention (n=16, causal): one block per (b*s, qh) ----------------
__global__ void time_attn_kernel(const bf16* __restrict__ qkv, bf16* __restrict__ obpk) {
    __shared__ float qs[16][65], ks[16][65], ps[16][17];
    int bs = blockIdx.x, qh = blockIdx.y, kh = qh >> 1;
    int tid = threadIdx.x;
    size_t rowbase = (size_t)bs * 16;
    #pragma unroll
    for (int i = 0; i < 4; ++i) {
        int idx = tid + 256 * i;
        int r = idx >> 6, d = idx & 63;
        qs[r][d] = __bfloat162float(qkv[(rowbase + r) * 2048 + qh * 64 + d]);
        ks[r][d] = __bfloat162float(qkv[(rowbase + r) * 2048 + 1024 + kh * 64 + d]);
    }
    __syncthreads();
    int i = tid >> 4, j = tid & 15;
    float dot = 0.f;
    #pragma unroll 16
    for (int d = 0; d < 64; ++d) dot += qs[i][d] * ks[j][d];
    float s = dot * 0.125f;
    float ex = __expf(s * 0.04f);
    s = 50.f * (ex - 1.f) / (ex + 1.f);
    if (j > i) s = -1e30f;
    float mx = s;
    mx = fmaxf(mx, __shfl_xor(mx, 1));
    mx = fmaxf(mx, __shfl_xor(mx, 2));
    mx = fmaxf(mx, __shfl_xor(mx, 4));
    mx = fmaxf(mx, __shfl_xor(mx, 8));
    float p = __expf(s - mx);
    float sum = p;
    sum += __shfl_xor(sum, 1);
    sum += __shfl_xor(sum, 2);
    sum += __shfl_xor(sum, 4);
    sum += __shfl_xor(sum, 8);
    ps[i][j] = p / sum;
    __syncthreads();
    #pragma unroll
    for (int ii = 0; ii < 4; ++ii) {
        int idx = tid + 256 * ii;
        int r = idx >> 6, d = idx & 63;
        float acc = 0.f;
        #pragma unroll
        for (int jj = 0; jj < 16; ++jj)
            acc += ps[r][jj] * __bfloat162float(qkv[(rowbase + jj) * 2048 + 1536 + kh * 64 + d]);
        obpk[pk_idx((int)(rowbase + r), qh * 64 + d, 128)] = __float2bfloat16(acc);
    }
}

// ---------------- host-side launch ----------------
extern "C" void kernel_launch(void* const* d_in, const int* in_sizes, int n_in,
                              void* d_out, int out_size, void* d_ws, size_t ws_size,
                              hipStream_t stream) {
    const float* tokens      = (const float*)d_in[0];
    const float* attn_norm_w = (const float*)d_in[1];
    const float* Wq          = (const float*)d_in[2];
    const float* Wk          = (const float*)d_in[3];
    const float* Wv          = (const float*)d_in[4];
    const float* q_gamma     = (const float*)d_in[5];
    const float* k_gamma     = (const float*)d_in[6];
    const float* Wo          = (const float*)d_in[7];
    const float* ff_norm_w   = (const float*)d_in[8];
    const float* W_in        = (const float*)d_in[9];
    const float* b_in        = (const float*)d_in[10];
    const float* W_out       = (const float*)d_in[11];
    const float* b_out       = (const float*)d_in[12];
    const float* final_w     = (const float*)d_in[13];

    float* x = (float*)d_out;
    char* ws = (char*)d_ws;

    // packed per-layer weights (reused each layer)
    bf16* wtqkv = (bf16*)ws;                                  // N=2048, kq8=64:  2 MB
    bf16* wto   = (bf16*)(ws + 2097152);                      // N=512,  kq8=128: 1 MB
    bf16* wtin  = (bf16*)(ws + 2097152 + 1048576);            // N=2816, kq8=64:  2.9 MB
    bf16* wtout = (bf16*)(ws + 2097152 + 1048576 + 2883584);  // N=512,  kq8=176: 1.4 MB
    size_t off = 2097152 + 1048576 + 2883584 + 1441792;
    bf16* h_pk  = (bf16*)(ws + off);   off += (size_t)520 * 64 * 128 * 2;    // 8.5 MB
    bf16* ob_pk = (bf16*)(ws + off);   off += (size_t)520 * 128 * 128 * 2;   // 17 MB
    bf16* qkv   = (bf16*)(ws + off);                                          // 33.7 MB
    bf16* glu_pk= (bf16*)(ws + off);   off += (size_t)NROWS * 2048 * 2;      // (alias)
    bf16* vt    = (bf16*)(ws + off);                                          // 9.4 MB

    hipMemcpyAsync(x, tokens, (size_t)NROWS * 512 * 4, hipMemcpyDeviceToDevice, stream);

    for (int l = 0; l < 8; ++l) {
        int is_time = ((l + 1) % 4 == 0) ? 1 : 0;
        wtrans_layer<<<3648, 256, 0, stream>>>(
            Wq + (size_t)l * 512 * 1024, Wk + (size_t)l * 512 * 512,
            Wv + (size_t)l * 512 * 512, Wo + (size_t)l * 1024 * 512,
            W_in + (size_t)l * 512 * DI2, W_out + (size_t)l * DII * 512,
            wtqkv, wto, wtin, wtout);

        // ---- attention block ----
        rms_kernel<1><<<NROWS, 256, 0, stream>>>(x, attn_norm_w + (size_t)l * 512, h_pk, is_time);
        mfma_gemm<1, 0, 128, 512><<<dim3(16, 65), 256, 0, stream>>>(
            (const short*)h_pk, (const short*)wtqkv, nullptr, qkv, 2048, NROWS,
            q_gamma + (size_t)l * 1024, k_gamma + (size_t)l * 512, is_time);
        if (is_time) {
            time_attn_kernel<<<dim3(514, 16), 256, 0, stream>>>(qkv, ob_pk);
            mfma_gemm<3, 1, 64, 1024><<<dim3(4, 129), 256, 0, stream>>>(
                (const short*)ob_pk, (const short*)wto, nullptr, x, 512, NROWS,
                nullptr, nullptr, 0);
        } else {
            vtrans_kernel<<<256, 256, 0, stream>>>(qkv, vt);
            space_attn_kernel<<<dim3(5, 16, 32), 256, 0, stream>>>(qkv, vt, ob_pk);
            mfma_gemm<3, 0, 64, 1024><<<dim3(4, 129), 256, 0, stream>>>(
                (const short*)ob_pk, (const short*)wto, nullptr, x, 512, NROWS,
                nullptr, nullptr, 0);
        }

        // ---- feed-forward block ----
        rms_kernel<1><<<NROWS, 256, 0, stream>>>(x, ff_norm_w + (size_t)l * 512, h_pk, 0);
        mfma_gemm<2, 0, 128, 512><<<dim3(22, 65), 256, 0, stream>>>(
            (const short*)h_pk, (const short*)wtin, b_in + (size_t)l * DI2, glu_pk, 0,
            NROWS, nullptr, nullptr, 0);
        mfma_gemm<3, 0, 64, GLUK><<<dim3(4, 129), 256, 0, stream>>>(
            (const short*)glu_pk, (const short*)wtout, b_out + (size_t)l * 512, x, 512,
            NROWS, nullptr, nullptr, 0);
    }

    rms_kernel<0><<<NROWS, 256, 0, stream>>>(x, final_w, x, 0);
}

// Round 10
// 2619.101 us; speedup vs baseline: 1.1981x; 1.0017x over previous
//
#include <hip/hip_runtime.h>
#include <hip/hip_bf16.h>
#include <math.h>

typedef __attribute__((ext_vector_type(8))) short short8;
typedef __attribute__((ext_vector_type(4))) float f32x4;
typedef __hip_bfloat16 bf16;

#define BB 2
#define TT 16
#define SSQ 257
#define DIMD 512
#define NROWS 8224          // B*T*S ( = 514 * 16 exactly)
#define DII 1365
#define DI2 2730
#define GLUK 1408           // glu K (44*32); kq8 = 176
#define SKP 288             // padded key count for space attn
#define EPSR 1.1920929e-07f

// per-layer packed weight slab (elements): qkv 2048*512 | wo 512*1024 |
// win 2816*512 | wout 512*1408
#define SLABE 3735552
#define SLABB 7471104

// Fragment-major packed layout: X_pk[t16][kq][l16][8] (shorts): frag load at
// (t16, kt) is lane-linear: base + ((t16*kq8 + kt*4)*128 + lane*8).

__device__ __forceinline__ short f2bfs(float x) {
    bf16 h = __float2bfloat16(x);
    return *reinterpret_cast<short*>(&h);
}

__device__ __forceinline__ size_t pk_idx(int row, int col, int kq8) {
    return ((size_t)((row >> 4) * kq8 + (col >> 3)) * 16 + (row & 15)) * 8 + (col & 7);
}

// ---------------- batched weight transpose fp32->bf16, packed ----------------
// blockIdx.y = slab index (layer = layer0 + y). grid.x = 3648 segment tiles.
__global__ void wtrans_layer(const float* __restrict__ wq0, const float* __restrict__ wk0,
                             const float* __restrict__ wv0, const float* __restrict__ wo0,
                             const float* __restrict__ win0, const float* __restrict__ wout0,
                             bf16* __restrict__ slabs, int layer0) {
    __shared__ float tile[32][33];
    int l = layer0 + blockIdx.y;
    const float* wq  = wq0  + (size_t)l * 512 * 1024;
    const float* wk  = wk0  + (size_t)l * 512 * 512;
    const float* wv  = wv0  + (size_t)l * 512 * 512;
    const float* wo  = wo0  + (size_t)l * 1024 * 512;
    const float* win = win0 + (size_t)l * 512 * DI2;
    const float* wout= wout0+ (size_t)l * DII * 512;
    bf16* dqkv = slabs + (size_t)blockIdx.y * SLABE;
    bf16* dwo  = dqkv + 1048576;
    bf16* dwin = dwo  + 524288;
    bf16* dwout= dwin + 1441792;

    int bid = blockIdx.x;
    const float* src; bf16* dst; int K, M, Kpad, interleave = 0, local, nbase = 0;
    if (bid < 512)       { src = wq;   dst = dqkv; K = 512;  M = 1024; Kpad = 512;  local = bid; }
    else if (bid < 768)  { src = wk;   dst = dqkv; K = 512;  M = 512;  Kpad = 512;  local = bid - 512;  nbase = 1024; }
    else if (bid < 1024) { src = wv;   dst = dqkv; K = 512;  M = 512;  Kpad = 512;  local = bid - 768;  nbase = 1536; }
    else if (bid < 1536) { src = wo;   dst = dwo;  K = 1024; M = 512;  Kpad = 1024; local = bid - 1024; }
    else if (bid < 2944) { src = win;  dst = dwin; K = 512;  M = 2730; Kpad = 512;  local = bid - 1536; interleave = 1; }
    else                 { src = wout; dst = dwout;K = 1365; M = 512;  Kpad = 1408; local = bid - 2944; }
    int tilesx = Kpad >> 5;
    int k0 = (local % tilesx) * 32, m0 = (local / tilesx) * 32;
    int tx = threadIdx.x & 31, ty = threadIdx.x >> 5;
    #pragma unroll
    for (int i = 0; i < 4; ++i) {
        int k = k0 + ty + 8 * i, m = m0 + tx;
        tile[ty + 8 * i][tx] = (k < K && m < M) ? src[(size_t)k * M + m] : 0.f;
    }
    __syncthreads();
    #pragma unroll
    for (int i = 0; i < 4; ++i) {
        int n = m0 + ty + 8 * i, k = k0 + tx;
        int nd = n;
        if (interleave) nd = (n < DII) ? 2 * n : ((n < DI2) ? 2 * (n - DII) + 1 : n);
        nd += nbase;
        dst[pk_idx(nd, k, Kpad >> 3)] = __float2bfloat16(tile[tx][ty + 8 * i]);
    }
}

// ---------------- RMSNorm (optional permuted read); bf16 out packed kq8=64 ----------------
template<int BF16OUT>
__global__ void rms_kernel(const float* __restrict__ x, const float* __restrict__ w,
                           void* __restrict__ out, int perm) {
    int r = blockIdx.x;
    int src = r;
    if (perm) {
        int t = r & 15; int rs = r >> 4; int s = rs % SSQ; int b = rs / SSQ;
        src = (b * TT + t) * SSQ + s;
    }
    const float* xr = x + (size_t)src * DIMD;
    int tid = threadIdx.x;
    float v0 = xr[tid], v1 = xr[tid + 256];
    __shared__ float red[256];
    red[tid] = v0 * v0 + v1 * v1;
    __syncthreads();
    for (int st = 128; st; st >>= 1) {
        if (tid < st) red[tid] += red[tid + st];
        __syncthreads();
    }
    float sc = rsqrtf(red[0] * (1.f / DIMD) + EPSR);
    if (BF16OUT) {
        bf16* o = (bf16*)out;
        o[pk_idx(r, tid, 64)]       = __float2bfloat16(v0 * sc * w[tid]);
        o[pk_idx(r, tid + 256, 64)] = __float2bfloat16(v1 * sc * w[tid + 256]);
    } else {
        float* o = (float*)out + (size_t)r * DIMD;
        o[tid] = v0 * sc * w[tid];
        o[tid + 256] = v1 * sc * w[tid + 256];
    }
}

// ---------------- MFMA bf16 GEMM, no LDS / no barriers, K templated ----------------
// Natural tile order (XCD swizzle measured harmful twice). Fully-unrolled
// K-loop, 2-buffer ping-pong stages; stage width: TM=128 -> 1 k-chunk (BK=32,
// register-bound, proven 80us), TM=64 -> 2 k-chunks (BK=64: 32 MFMA/stage
// covers ~460cyc at 3 waves/SIMD). EPI: 1 = qkv + fused l2norm/gamma/rotary;
// 2 = glu packed out (tanh-gelu); 3 = fp32 accumulate (+bias, opt PERM).
template<int EPI, int PERM, int TM, int K>
__global__ __launch_bounds__(256, 2)
void mfma_gemm(const short* __restrict__ Apk, const short* __restrict__ Bpk,
               const float* __restrict__ bias, void* __restrict__ C, int ldc,
               int nrow,
               const float* __restrict__ qg, const float* __restrict__ kg, int rotary) {
    constexpr int MI = TM / 32;
    constexpr int kq8 = K / 8;
    constexpr int CPS = (TM == 64) ? 2 : 1;    // k-chunks per pipeline stage
    constexpr int NST = (K / 32) / CPS;        // stages (always even counts)
    int tid = threadIdx.x;
    int wave = tid >> 6, lane = tid & 63;
    int quad = lane >> 4, l16 = lane & 15;
    int m0 = blockIdx.y * TM, n0 = blockIdx.x * 128;
    int wm = (wave & 1) * (TM / 2), wn = (wave >> 1) * 64;
    int mt0 = (m0 + wm) >> 4, nt0 = (n0 + wn) >> 4;

    const short* ab[MI]; const short* bb[4];
    #pragma unroll
    for (int mi = 0; mi < MI; ++mi) ab[mi] = Apk + (size_t)(mt0 + mi) * kq8 * 128 + lane * 8;
    #pragma unroll
    for (int nj = 0; nj < 4; ++nj)  bb[nj] = Bpk + (size_t)(nt0 + nj) * kq8 * 128 + lane * 8;

    f32x4 zero4 = {0.f, 0.f, 0.f, 0.f};
    f32x4 acc[MI][4];
    #pragma unroll
    for (int i = 0; i < MI; ++i)
        #pragma unroll
        for (int j = 0; j < 4; ++j) acc[i][j] = zero4;

    short8 Ab[2][CPS][MI], Bb[2][CPS][4];
    auto loadst = [&](int buf, int st) {
        #pragma unroll
        for (int c = 0; c < CPS; ++c) {
            size_t off = (size_t)(st * CPS + c) * 512;
            #pragma unroll
            for (int mi = 0; mi < MI; ++mi) Ab[buf][c][mi] = *(const short8*)(ab[mi] + off);
            #pragma unroll
            for (int nj = 0; nj < 4; ++nj)  Bb[buf][c][nj] = *(const short8*)(bb[nj] + off);
        }
    };
    loadst(0, 0);
    #pragma unroll
    for (int st = 0; st < NST; ++st) {
        if (st + 1 < NST) loadst((st + 1) & 1, st + 1);
        const int b = st & 1;
        #pragma unroll
        for (int c = 0; c < CPS; ++c)
            #pragma unroll
            for (int mi = 0; mi < MI; ++mi)
                #pragma unroll
                for (int nj = 0; nj < 4; ++nj)
                    acc[mi][nj] = __builtin_amdgcn_mfma_f32_16x16x32_bf16(
                        Ab[b][c][mi], Bb[b][c][nj], acc[mi][nj], 0, 0, 0);
    }

    if constexpr (EPI == 1) {
        // qkv output: cols wn..wn+63 = exactly one head.
        int head = (n0 + wn) >> 6;          // 0..15 q, 16..23 k, 24..31 v
        float gl0 = 0.f, gl1 = 0.f, gl2 = 0.f, gl3 = 0.f, inv0 = 0.f, inv1 = 0.f;
        if (head < 24) {
            const float* g = head < 16 ? qg + head * 64 : kg + (head - 16) * 64;
            gl0 = (g[l16] + 1.f) * 8.f;
            gl1 = (g[16 + l16] + 1.f) * 8.f;
            gl2 = (g[32 + l16] + 1.f) * 8.f;
            gl3 = (g[48 + l16] + 1.f) * 8.f;
            if (rotary) {
                inv0 = __expf(-(float)l16 * 0.28782313662425572f);        // ln(1e4)/32
                inv1 = __expf(-(float)(l16 + 16) * 0.28782313662425572f);
            }
        }
        #pragma unroll
        for (int mi = 0; mi < MI; ++mi) {
            #pragma unroll
            for (int e = 0; e < 4; ++e) {
                int row = m0 + wm + mi * 16 + quad * 4 + e;
                float v0 = acc[mi][0][e], v1 = acc[mi][1][e];
                float v2 = acc[mi][2][e], v3 = acc[mi][3][e];
                if (head < 24) {
                    float ss = v0 * v0 + v1 * v1 + v2 * v2 + v3 * v3;
                    ss += __shfl_xor(ss, 1); ss += __shfl_xor(ss, 2);
                    ss += __shfl_xor(ss, 4); ss += __shfl_xor(ss, 8);
                    float invn = 1.f / fmaxf(sqrtf(ss), 1e-12f);
                    v0 *= invn * gl0; v1 *= invn * gl1;
                    v2 *= invn * gl2; v3 *= invn * gl3;
                    if (rotary) {
                        float tt = (float)(row & 15);
                        float a0v = tt * inv0, a1v = tt * inv1;
                        float c0 = __cosf(a0v), s0 = __sinf(a0v);
                        float c1 = __cosf(a1v), s1 = __sinf(a1v);
                        float n0v = v0 * c0 - v2 * s0;
                        float n1v = v1 * c1 - v3 * s1;
                        float n2v = v2 * c0 + v0 * s0;
                        float n3v = v3 * c1 + v1 * s1;
                        v0 = n0v; v1 = n1v; v2 = n2v; v3 = n3v;
                    }
                }
                if (row < nrow) {
                    bf16* p = (bf16*)C + (size_t)row * ldc + n0 + wn + l16;
                    p[0]  = __float2bfloat16(v0);
                    p[16] = __float2bfloat16(v1);
                    p[32] = __float2bfloat16(v2);
                    p[48] = __float2bfloat16(v3);
                }
            }
        }
    } else if constexpr (EPI == 2) {
        // interleaved a/g; tanh-form gelu; write packed glu (kq8=176) at j=col/2.
        #pragma unroll
        for (int mi = 0; mi < MI; ++mi) {
            #pragma unroll
            for (int e = 0; e < 4; ++e) {
                int row = m0 + wm + mi * 16 + quad * 4 + e;
                #pragma unroll
                for (int nj = 0; nj < 4; ++nj) {
                    int col = n0 + wn + nj * 16 + l16;
                    int j = col >> 1;
                    float b = (j < DII) ? ((col & 1) ? bias[DII + j] : bias[j]) : 0.f;
                    float v = acc[mi][nj][e] + b;
                    float prt = __shfl_xor(v, 1);
                    if (!(l16 & 1) && row < nrow) {
                        float gv = prt;
                        float u = 0.7978845608028654f * (gv + 0.044715f * gv * gv * gv);
                        float e2u = __expf(2.f * u);
                        float th = 1.f - 2.f * __builtin_amdgcn_rcpf(e2u + 1.f);
                        float glu = v * 0.5f * gv * (1.f + th);
                        ((bf16*)C)[pk_idx(row, j, 176)] = __float2bfloat16(glu);
                    }
                }
            }
        }
    } else {
        #pragma unroll
        for (int mi = 0; mi < MI; ++mi) {
            #pragma unroll
            for (int e = 0; e < 4; ++e) {
                int row = m0 + wm + mi * 16 + quad * 4 + e;
                if (row >= nrow) continue;
                int orow = row;
                if (PERM) {
                    int tt = row & 15; int rs = row >> 4; int s = rs % SSQ; int b = rs / SSQ;
                    orow = (b * TT + tt) * SSQ + s;
                }
                #pragma unroll
                for (int nj = 0; nj < 4; ++nj) {
                    int col = n0 + wn + nj * 16 + l16;
                    float v = acc[mi][nj][e];
                    if (bias) v += bias[col];
                    ((float*)C)[(size_t)orow * ldc + col] += v;
                }
            }
        }
    }
}

// ---------------- V transpose via LDS tile: vt[bt*8+kh][64][SKP] bf16 ----------------
__global__ void vtrans_kernel(const bf16* __restrict__ qkv, bf16* __restrict__ vt) {
    __shared__ bf16 tile[32][72];
    int bkh = blockIdx.x;          // bt*8 + kh
    int bt = bkh >> 3, kh = bkh & 7;
    int tid = threadIdx.x;
    bf16* vb = vt + (size_t)bkh * 64 * SKP;
    for (int kc = 0; kc < 9; ++kc) {
        #pragma unroll
        for (int i = 0; i < 8; ++i) {
            int idx = tid + 256 * i;   // 0..2047 = 32 keys x 64 d
            int kl = idx >> 6, d = idx & 63;
            int key = kc * 32 + kl;
            bf16 v = __float2bfloat16(0.f);
            if (key < SSQ)
                v = qkv[((size_t)(bt * SSQ + key)) * 2048 + 1536 + kh * 64 + d];
            tile[kl][d] = v;
        }
        __syncthreads();
        #pragma unroll
        for (int i = 0; i < 8; ++i) {
            int idx = tid + 256 * i;   // 64 d x 32 keys
            int dl = idx >> 5, kl = idx & 31;
            vb[(size_t)dl * SKP + kc * 32 + kl] = tile[kl][dl];
        }
        __syncthreads();
    }
}

// ---------------- space attention: S^T in registers, zero LDS; ob packed out ----------------
__global__ __launch_bounds__(256)
void space_attn_kernel(const bf16* __restrict__ qkv, const bf16* __restrict__ vt,
                       bf16* __restrict__ obpk) {
    int qt = blockIdx.x, qh = blockIdx.y, bt = blockIdx.z;
    int kh = qh >> 1;
    int tid = threadIdx.x, wave = tid >> 6, lane = tid & 63;
    int quad = lane >> 4, l16 = lane & 15;
    int q0w = qt * 64 + wave * 16;
    int q = q0w + l16;
    int qc = q > 256 ? 256 : q;
    const short* qbase = (const short*)qkv + (size_t)bt * SSQ * 2048;
    const short* qp = qbase + (size_t)qc * 2048 + qh * 64;
    short8 bq0 = *(const short8*)(qp + quad * 8);
    short8 bq1 = *(const short8*)(qp + 32 + quad * 8);
    f32x4 zero4 = {0.f, 0.f, 0.f, 0.f};
    f32x4 sc[18];

    #pragma unroll
    for (int kt = 0; kt < 17; ++kt) {
        int keyl = kt * 16 + l16; if (keyl > 256) keyl = 256;
        const short* kp = qbase + (size_t)keyl * 2048 + 1024 + kh * 64;
        short8 ak0 = *(const short8*)(kp + quad * 8);
        short8 ak1 = *(const short8*)(kp + 32 + quad * 8);
        f32x4 c = zero4;
        c = __builtin_amdgcn_mfma_f32_16x16x32_bf16(ak0, bq0, c, 0, 0, 0);
        c = __builtin_amdgcn_mfma_f32_16x16x32_bf16(ak1, bq1, c, 0, 0, 0);
        #pragma unroll
        for (int e = 0; e < 4; ++e) {
            float e2x = __expf(c[e] * 0.005f);
            float v = 50.f - 100.f * __builtin_amdgcn_rcpf(e2x + 1.f);
            if (kt == 16) {
                bool valid = (e == 0) && (quad == 0) && (q == 256);
                v = valid ? v : -1e30f;
            }
            c[e] = v;
        }
        sc[kt] = c;
    }

    float mx = -1e30f;
    #pragma unroll
    for (int kt = 0; kt < 17; ++kt)
        mx = fmaxf(mx, fmaxf(fmaxf(sc[kt][0], sc[kt][1]), fmaxf(sc[kt][2], sc[kt][3])));
    mx = fmaxf(mx, __shfl_xor(mx, 16));
    mx = fmaxf(mx, __shfl_xor(mx, 32));
    float sum = 0.f;
    #pragma unroll
    for (int kt = 0; kt < 17; ++kt) {
        #pragma unroll
        for (int e = 0; e < 4; ++e) {
            float p = __expf(sc[kt][e] - mx);
            sc[kt][e] = p;
            sum += p;
        }
    }
    #pragma unroll
    for (int e = 0; e < 4; ++e) sc[17][e] = 0.f;
    sum += __shfl_xor(sum, 16);
    sum += __shfl_xor(sum, 32);
    float inv = __builtin_amdgcn_rcpf(sum);
    f32x4 inv4;
    #pragma unroll
    for (int e = 0; e < 4; ++e) inv4[e] = __shfl(inv, quad * 4 + e);

    f32x4 oacc[4];
    #pragma unroll
    for (int nt = 0; nt < 4; ++nt) oacc[nt] = zero4;
    const short* vbp = (const short*)vt + ((size_t)(bt * 8 + kh) * 64 + l16) * SKP;
    #pragma unroll
    for (int c8 = 0; c8 < 9; ++c8) {
        short8 pb;
        #pragma unroll
        for (int j = 0; j < 8; ++j) {
            int src_lane = ((quad & 1) * 2 + (j >> 2)) * 16 + l16;
            float v0 = __shfl(sc[2 * c8][j & 3], src_lane);
            float v1 = __shfl(sc[2 * c8 + 1][j & 3], src_lane);
            pb[j] = f2bfs(quad < 2 ? v0 : v1);
        }
        #pragma unroll
        for (int nt = 0; nt < 4; ++nt) {
            short8 av = *(const short8*)(vbp + (size_t)(nt * 16) * SKP + c8 * 32 + quad * 8);
            oacc[nt] = __builtin_amdgcn_mfma_f32_16x16x32_bf16(pb, av, oacc[nt], 0, 0, 0);
        }
    }

    #pragma unroll
    for (int e = 0; e < 4; ++e) {
        int qq = q0w + quad * 4 + e;
        if (qq <= 256) {
            int row = bt * SSQ + qq;
            float s = inv4[e];
            #pragma unroll
            for (int nt = 0; nt < 4; ++nt)
                obpk[pk_idx(row, qh * 64 + nt * 16 + l16, 128)] =
                    __float2bfloat16(oacc[nt][e] * s);
        }
    }
}

// ---------------- time attention (n=16, causal): one block per (b*s, qh) ----------------
__global__ void time_attn_kernel(const bf16* __restrict__ qkv, bf16* __restrict__ obpk) {
    __shared__ float qs[16][65], ks[16][65], ps[16][17];
    int bs = blockIdx.x, qh = blockIdx.y, kh = qh >> 1;
    int tid = threadIdx.x;
    size_t rowbase = (size_t)bs * 16;
    #pragma unroll
    for (int i = 0; i < 4; ++i) {
        int idx = tid + 256 * i;
        int r = idx >> 6, d = idx & 63;
        qs[r][d] = __bfloat162float(qkv[(rowbase + r) * 2048 + qh * 64 + d]);
        ks[r][d] = __bfloat162float(qkv[(rowbase + r) * 2048 + 1024 + kh * 64 + d]);
    }
    __syncthreads();
    int i = tid >> 4, j = tid & 15;
    float dot = 0.f;
    #pragma unroll 16
    for (int d = 0; d < 64; ++d) dot += qs[i][d] * ks[j][d];
    float s = dot * 0.125f;
    float ex = __expf(s * 0.04f);
    s = 50.f * (ex - 1.f) / (ex + 1.f);
    if (j > i) s = -1e30f;
    float mx = s;
    mx = fmaxf(mx, __shfl_xor(mx, 1));
    mx = fmaxf(mx, __shfl_xor(mx, 2));
    mx = fmaxf(mx, __shfl_xor(mx, 4));
    mx = fmaxf(mx, __shfl_xor(mx, 8));
    float p = __expf(s - mx);
    float sum = p;
    sum += __shfl_xor(sum, 1);
    sum += __shfl_xor(sum, 2);
    sum += __shfl_xor(sum, 4);
    sum += __shfl_xor(sum, 8);
    ps[i][j] = p / sum;
    __syncthreads();
    #pragma unroll
    for (int ii = 0; ii < 4; ++ii) {
        int idx = tid + 256 * ii;
        int r = idx >> 6, d = idx & 63;
        float acc = 0.f;
        #pragma unroll
        for (int jj = 0; jj < 16; ++jj)
            acc += ps[r][jj] * __bfloat162float(qkv[(rowbase + jj) * 2048 + 1536 + kh * 64 + d]);
        obpk[pk_idx((int)(rowbase + r), qh * 64 + d, 128)] = __float2bfloat16(acc);
    }
}

// ---------------- host-side launch ----------------
extern "C" void kernel_launch(void* const* d_in, const int* in_sizes, int n_in,
                              void* d_out, int out_size, void* d_ws, size_t ws_size,
                              hipStream_t stream) {
    const float* tokens      = (const float*)d_in[0];
    const float* attn_norm_w = (const float*)d_in[1];
    const float* Wq          = (const float*)d_in[2];
    const float* Wk          = (const float*)d_in[3];
    const float* Wv          = (const float*)d_in[4];
    const float* q_gamma     = (const float*)d_in[5];
    const float* k_gamma     = (const float*)d_in[6];
    const float* Wo          = (const float*)d_in[7];
    const float* ff_norm_w   = (const float*)d_in[8];
    const float* W_in        = (const float*)d_in[9];
    const float* b_in        = (const float*)d_in[10];
    const float* W_out       = (const float*)d_in[11];
    const float* b_out       = (const float*)d_in[12];
    const float* final_w     = (const float*)d_in[13];

    float* x = (float*)d_out;
    char* ws = (char*)d_ws;

    // rest-of-workspace sizes
    const size_t REST = 8519680ull + 17039360ull + 33685504ull + 9437184ull;
    // all-layer weight slabs if workspace allows; else single reused slab
    int nslab = (ws_size >= (size_t)8 * SLABB + REST) ? 8 : 1;

    bf16* slabs = (bf16*)ws;
    char* rest = ws + (size_t)nslab * SLABB;
    bf16* h_pk  = (bf16*)rest;                       // [520][64][128]  8.5 MB
    bf16* ob_pk = (bf16*)(rest + 8519680);           // [520][128][128] 17 MB
    bf16* qkv   = (bf16*)(rest + 8519680 + 17039360);          // [N][2048]
    bf16* glu_pk= qkv;                                          // FF-phase alias
    bf16* vt    = (bf16*)(rest + 8519680 + 17039360 + 33685504);// [256][64][288]

    hipMemcpyAsync(x, tokens, (size_t)NROWS * 512 * 4, hipMemcpyDeviceToDevice, stream);

    if (nslab == 8)
        wtrans_layer<<<dim3(3648, 8), 256, 0, stream>>>(Wq, Wk, Wv, Wo, W_in, W_out,
                                                        slabs, 0);

    for (int l = 0; l < 8; ++l) {
        int is_time = ((l + 1) % 4 == 0) ? 1 : 0;
        if (nslab == 1)
            wtrans_layer<<<dim3(3648, 1), 256, 0, stream>>>(Wq, Wk, Wv, Wo, W_in, W_out,
                                                            slabs, l);
        bf16* slab = slabs + (size_t)(nslab == 8 ? l : 0) * SLABE;
        const short* wtqkv = (const short*)slab;
        const short* wto   = (const short*)(slab + 1048576);
        const short* wtin  = (const short*)(slab + 1572864);
        const short* wtout = (const short*)(slab + 3014656);

        // ---- attention block ----
        rms_kernel<1><<<NROWS, 256, 0, stream>>>(x, attn_norm_w + (size_t)l * 512, h_pk, is_time);
        mfma_gemm<1, 0, 128, 512><<<dim3(16, 65), 256, 0, stream>>>(
            (const short*)h_pk, wtqkv, nullptr, qkv, 2048, NROWS,
            q_gamma + (size_t)l * 1024, k_gamma + (size_t)l * 512, is_time);
        if (is_time) {
            time_attn_kernel<<<dim3(514, 16), 256, 0, stream>>>(qkv, ob_pk);
            mfma_gemm<3, 1, 64, 1024><<<dim3(4, 129), 256, 0, stream>>>(
                (const short*)ob_pk, wto, nullptr, x, 512, NROWS, nullptr, nullptr, 0);
        } else {
            vtrans_kernel<<<256, 256, 0, stream>>>(qkv, vt);
            space_attn_kernel<<<dim3(5, 16, 32), 256, 0, stream>>>(qkv, vt, ob_pk);
            mfma_gemm<3, 0, 64, 1024><<<dim3(4, 129), 256, 0, stream>>>(
                (const short*)ob_pk, wto, nullptr, x, 512, NROWS, nullptr, nullptr, 0);
        }

        // ---- feed-forward block ----
        rms_kernel<1><<<NROWS, 256, 0, stream>>>(x, ff_norm_w + (size_t)l * 512, h_pk, 0);
        mfma_gemm<2, 0, 128, 512><<<dim3(22, 65), 256, 0, stream>>>(
            (const short*)h_pk, wtin, b_in + (size_t)l * DI2, glu_pk, 0,
            NROWS, nullptr, nullptr, 0);
        mfma_gemm<3, 0, 64, GLUK><<<dim3(4, 129), 256, 0, stream>>>(
            (const short*)glu_pk, wtout, b_out + (size_t)l * 512, x, 512,
            NROWS, nullptr, nullptr, 0);
    }

    rms_kernel<0><<<NROWS, 256, 0, stream>>>(x, final_w, x, 0);
}